// Round 6
// baseline (201.990 us; speedup 1.0000x reference)
//
#include <hip/hip_runtime.h>
#include <hip/hip_bf16.h>

// CaMLoss fused forward for MI355X (gfx950).
// B=4096, D=2048, C=1024. Assumes D%512==0, B%256==0, C%256==0 for the pd pass.
// enb/cnb stored SLOT-SWIZZLED: within each 64-elem chunk of row i, 8-elem slot
// s lives at s ^ (i&7). Linear global_load_lds staging lands swizzled in LDS;
// ds_read at idx ^ ((row&7)<<3) is bank-conflict-free (verified: 0 conflicts).
// k_pd_all (R6): 256^2 tile, BK=64, 8 waves, dbuf 128KB dynamic LDS, 4 quadrant
// phases per K-tile (12 ds_read + 16 MFMA + setprio), counted vmcnt(8) at
// K-tile boundaries (T3+T4; never drains to 0 in the main loop).

typedef __attribute__((ext_vector_type(8))) short short8;
typedef __attribute__((ext_vector_type(4))) float f32x4;

#define BIGF 1e6f
#define EPSC 1e-12f
#define MAXDD 16

__device__ __forceinline__ float bf2f(unsigned short u){
  unsigned int x = ((unsigned int)u) << 16;
  return __uint_as_float(x);
}
__device__ __forceinline__ unsigned short f2bf(float f){
  __hip_bfloat16 h = __float2bfloat16(f);
  return *reinterpret_cast<unsigned short*>(&h);
}

__device__ __forceinline__ float block_reduce_sum(float v){
  __shared__ float red[4];
  int tid = threadIdx.x;
  __syncthreads();
  #pragma unroll
  for (int s = 32; s; s >>= 1) v += __shfl_xor(v, s);
  if ((tid & 63) == 0) red[tid >> 6] = v;
  __syncthreads();
  return red[0] + red[1] + red[2] + red[3];
}

// async global->LDS, 16B per lane, wave-uniform LDS base + lane*16
#define GLL16(gptr, lptr) \
  __builtin_amdgcn_global_load_lds( \
      (const __attribute__((address_space(1))) unsigned int*)(gptr), \
      (__attribute__((address_space(3))) unsigned int*)(lptr), 16, 0, 0)

// ---------------- setup: init stats + per-class counts + member lists ----------------
// Race-free across blocks: cnt[c] computed by direct count (no atomics, no
// separate zeroing kernel); members written by rank (deterministic).
__global__ void k_setup(const int* __restrict__ labels, int* cnt, int* members,
                        unsigned* mn0, unsigned* mx0, unsigned* fl0,
                        unsigned* mn1, unsigned* mx1, unsigned* fl1,
                        int B, int C, int MMAX){
  extern __shared__ int slab[];
  for (int j = threadIdx.x; j < B; j += blockDim.x) slab[j] = labels[j];
  __syncthreads();
  int i = blockIdx.x * blockDim.x + threadIdx.x;
  unsigned bigbits = __float_as_uint(BIGF);
  if (i < B){
    mn0[i] = bigbits; mx0[i] = 0u; fl0[i] = 0u;
    mn1[i] = bigbits; mx1[i] = 0u; fl1[i] = 0u;
  }
  if (i < C){                      // total count of class i
    int c = 0, j = 0;
    int full = B & ~3;
    for (; j < full; j += 4){
      int4 l4 = *reinterpret_cast<const int4*>(&slab[j]);
      c += (l4.x == i) + (l4.y == i) + (l4.z == i) + (l4.w == i);
    }
    for (; j < B; ++j) c += (slab[j] == i);
    cnt[i] = c;
  }
  if (i < B){                      // rank among earlier same-label indices
    int c = slab[i];
    int rank = 0, j = 0;
    int full = i & ~3;
    for (; j < full; j += 4){
      int4 l4 = *reinterpret_cast<const int4*>(&slab[j]);
      rank += (l4.x == c) + (l4.y == c) + (l4.z == c) + (l4.w == c);
    }
    for (; j < i; ++j) rank += (slab[j] == c);
    if (rank < MMAX) members[c * MMAX + rank] = i;
  }
}

// ---------------- prep: normalize embeddings + centers (merged) ----------------
template<int R>   // R = D/512
__global__ __launch_bounds__(256) void k_prep(const float* __restrict__ emb,
    const float* __restrict__ cval, const float* __restrict__ ccnt,
    const int* __restrict__ cnt, const int* __restrict__ members,
    unsigned short* __restrict__ enb, unsigned short* __restrict__ cnb,
    float* __restrict__ exx, float* __restrict__ cxx,
    int D, int MMAX, int nbNorm){
  int w = threadIdx.x >> 6, lane = threadIdx.x & 63;
  if ((int)blockIdx.x < nbNorm){
    // ---- normalize one row per wave ----
    int i = blockIdx.x * 4 + w;
    const float* row = emb + (size_t)i * D;
    float v[R][8];
    float ss = 0.f;
    #pragma unroll
    for (int r = 0; r < R; ++r){
      int base = r * 512 + lane * 8;
      float4 a = *reinterpret_cast<const float4*>(&row[base]);
      float4 b = *reinterpret_cast<const float4*>(&row[base + 4]);
      v[r][0]=a.x; v[r][1]=a.y; v[r][2]=a.z; v[r][3]=a.w;
      v[r][4]=b.x; v[r][5]=b.y; v[r][6]=b.z; v[r][7]=b.w;
      #pragma unroll
      for (int k = 0; k < 8; ++k) ss += v[r][k] * v[r][k];
    }
    #pragma unroll
    for (int s = 1; s < 64; s <<= 1) ss += __shfl_xor(ss, s);
    float inv = 1.f / (sqrtf(ss) + EPSC);
    unsigned short* orow = enb + (size_t)i * D;
    int xr = (i & 7) << 3;
    #pragma unroll
    for (int r = 0; r < R; ++r){
      int base = (r * 512 + lane * 8) ^ xr;
      short8 o;
      #pragma unroll
      for (int k = 0; k < 8; ++k) o[k] = (short)f2bf(v[r][k] * inv);
      *reinterpret_cast<short8*>(&orow[base]) = o;
    }
    if (lane == 0) exx[i] = ss * inv * inv;
  } else {
    // ---- one center per wave ----
    int c = ((int)blockIdx.x - nbNorm) * 4 + w;
    int n = cnt[c], m = n < MMAX ? n : MMAX;
    float acc[R][8];
    #pragma unroll
    for (int r = 0; r < R; ++r)
      #pragma unroll
      for (int k = 0; k < 8; ++k) acc[r][k] = 0.f;
    for (int e = 0; e < m; ++e){
      const float* row = emb + (size_t)members[c * MMAX + e] * D;
      #pragma unroll
      for (int r = 0; r < R; ++r){
        int base = r * 512 + lane * 8;
        float4 a = *reinterpret_cast<const float4*>(&row[base]);
        float4 b = *reinterpret_cast<const float4*>(&row[base + 4]);
        acc[r][0]+=a.x; acc[r][1]+=a.y; acc[r][2]+=a.z; acc[r][3]+=a.w;
        acc[r][4]+=b.x; acc[r][5]+=b.y; acc[r][6]+=b.z; acc[r][7]+=b.w;
      }
    }
    float cf = (float)n;
    float ss = 0.f;
    #pragma unroll
    for (int r = 0; r < R; ++r){
      int base = r * 512 + lane * 8;
      float4 u0 = *reinterpret_cast<const float4*>(&ccnt[(size_t)c * D + base]);
      float4 u1 = *reinterpret_cast<const float4*>(&ccnt[(size_t)c * D + base + 4]);
      float4 w0 = *reinterpret_cast<const float4*>(&cval[(size_t)c * D + base]);
      float4 w1 = *reinterpret_cast<const float4*>(&cval[(size_t)c * D + base + 4]);
      float uc[8] = {u0.x,u0.y,u0.z,u0.w,u1.x,u1.y,u1.z,u1.w};
      float wv[8] = {w0.x,w0.y,w0.z,w0.w,w1.x,w1.y,w1.z,w1.w};
      #pragma unroll
      for (int k = 0; k < 8; ++k){
        float u = uc[k] + cf;
        float vv = wv[k] + acc[r][k];
        float ce = (u > 0.f) ? (vv / fmaxf(u, 1.f)) : 0.f;
        acc[r][k] = ce; ss += ce * ce;
      }
    }
    #pragma unroll
    for (int s = 1; s < 64; s <<= 1) ss += __shfl_xor(ss, s);
    float inv = 1.f / (sqrtf(ss) + EPSC);
    int xr = (c & 7) << 3;
    #pragma unroll
    for (int r = 0; r < R; ++r){
      int base = (r * 512 + lane * 8) ^ xr;
      short8 o;
      #pragma unroll
      for (int k = 0; k < 8; ++k) o[k] = (short)f2bf(acc[r][k] * inv);
      *reinterpret_cast<short8*>(&cnb[(size_t)c * D + base]) = o;
    }
    if (lane == 0) cxx[c] = ss * inv * inv;
  }
}

// ---------------- hardest positive: one wave per row ----------------
template<int NCH>
__global__ __launch_bounds__(256) void k_hpos(const unsigned short* __restrict__ enb,
    const unsigned short* __restrict__ cnb, const float* __restrict__ exx,
    const float* __restrict__ cxx, const int* __restrict__ labels,
    const int* __restrict__ cnt, const int* __restrict__ members,
    float* __restrict__ hpos, int D, int MMAX){
  int w = threadIdx.x >> 6, lane = threadIdx.x & 63;
  int i = blockIdx.x * 4 + w;
  int li = labels[i];
  const unsigned short* arow = enb + (size_t)i * D;
  int xri = (i & 7) << 3;
  float av[NCH][8];
  #pragma unroll
  for (int ch = 0; ch < NCH; ++ch){
    short8 a8 = *reinterpret_cast<const short8*>(&arow[(ch * 512 + lane * 8) ^ xri]);
    #pragma unroll
    for (int k = 0; k < 8; ++k) av[ch][k] = bf2f((unsigned short)a8[k]);
  }
  float xi = exx[i];
  float hp = 0.f;
  int m = cnt[li] < MMAX ? cnt[li] : MMAX;
  for (int e = 0; e < m; ++e){
    int j = members[li * MMAX + e];
    if (j == i) continue;                     // wave-uniform
    const unsigned short* brow = enb + (size_t)j * D;
    int xrj = (j & 7) << 3;
    float p = 0.f;
    #pragma unroll
    for (int ch = 0; ch < NCH; ++ch){
      short8 b8 = *reinterpret_cast<const short8*>(&brow[(ch * 512 + lane * 8) ^ xrj]);
      #pragma unroll
      for (int k = 0; k < 8; ++k) p += av[ch][k] * bf2f((unsigned short)b8[k]);
    }
    #pragma unroll
    for (int s = 1; s < 64; s <<= 1) p += __shfl_xor(p, s);
    float d2 = xi + exx[j] - 2.f * p;
    hp = fmaxf(hp, sqrtf(fmaxf(d2, EPSC)));
  }
  {
    const unsigned short* brow = cnb + (size_t)li * D;
    int xrc = (li & 7) << 3;
    float p = 0.f;
    #pragma unroll
    for (int ch = 0; ch < NCH; ++ch){
      short8 b8 = *reinterpret_cast<const short8*>(&brow[(ch * 512 + lane * 8) ^ xrc]);
      #pragma unroll
      for (int k = 0; k < 8; ++k) p += av[ch][k] * bf2f((unsigned short)b8[k]);
    }
    #pragma unroll
    for (int s = 1; s < 64; s <<= 1) p += __shfl_xor(p, s);
    float d2 = xi + cxx[li] - 2.f * p;
    hp = fmaxf(hp, sqrtf(fmaxf(d2, EPSC)));
  }
  if (lane == 0) hpos[i] = hp;
}

// ---------------- merged distance pass: 256^2 tiles, 8-phase counted-vmcnt ----------------
__global__ __launch_bounds__(512, 2) void k_pd_all(
    const unsigned short* __restrict__ enb,
    const unsigned short* __restrict__ cnb,
    const float* __restrict__ exx, const float* __restrict__ cxx,
    const int* __restrict__ labels, const float* __restrict__ hpos,
    unsigned* __restrict__ mn0, unsigned* __restrict__ mx0, unsigned* __restrict__ fl0,
    unsigned* __restrict__ mn1, unsigned* __restrict__ mx1, unsigned* __restrict__ fl1,
    int D, int nTri, int nCx)
{
  extern __shared__ unsigned short sm[];           // 128 KiB dynamic
  unsigned short* ldsA = sm;                       // [2][256][64]
  unsigned short* ldsB = sm + 2 * 256 * 64;        // [2][256][64]

  // bijective XCD swizzle (m204)
  const int nwg = gridDim.x;
  const int orig = blockIdx.x;
  const int q8 = nwg >> 3, r8 = nwg & 7;
  const int xcd = orig & 7, idx = orig >> 3;
  const int t = (xcd < r8 ? xcd * (q8 + 1) : r8 * (q8 + 1) + (xcd - r8) * q8) + idx;

  const bool pdc = (t >= nTri);
  int bx, by;
  if (!pdc){
    int b = (int)((sqrtf(8.f * (float)t + 1.f) - 1.f) * 0.5f);
    while ((b + 1) * (b + 2) / 2 <= t) ++b;
    while (b * (b + 1) / 2 > t) --b;
    by = b; bx = t - b * (b + 1) / 2;              // bx <= by
  } else {
    int u = t - nTri;
    by = u / nCx; bx = u - by * nCx;
  }
  const unsigned short* cmat = pdc ? cnb : enb;
  const float* cxv = pdc ? cxx : exx;
  unsigned* mnv = pdc ? mn1 : mn0;
  unsigned* mxv = pdc ? mx1 : mx0;
  unsigned* flv = pdc ? fl1 : fl0;

  const int j0 = bx * 256, i0 = by * 256;
  const int tid = threadIdx.x;
  const int wid = tid >> 6, lane = tid & 63;
  const int wr = wid >> 2, wc = wid & 3;           // 2M x 4N waves: 128x64 out each
  const int lr = lane & 15, lg = lane >> 4;

  // staging: wave wid stages rows [wid*32, wid*32+32) of both A and B, 8 rows/GLL16
  const int srow = wid * 32 + (lane >> 3);
  const int scol = (lane & 7) * 8;
  const unsigned short* gA = enb  + (size_t)(i0 + srow) * D + scol;
  const unsigned short* gB = cmat + (size_t)(j0 + srow) * D + scol;

  f32x4 zero = {0.f, 0.f, 0.f, 0.f};
  f32x4 acc[8][4];
  #pragma unroll
  for (int m = 0; m < 8; ++m)
    #pragma unroll
    for (int n = 0; n < 4; ++n) acc[m][n] = zero;

  auto STAGE = [&](int kt, int cur){               // 8 loads per wave
    unsigned short* dA = ldsA + cur * (256 * 64);
    unsigned short* dB = ldsB + cur * (256 * 64);
    #pragma unroll
    for (int it2 = 0; it2 < 4; ++it2){
      GLL16(gA + (size_t)kt + (size_t)it2 * 8 * D, dA + (wid * 32 + it2 * 8) * 64);
      GLL16(gB + (size_t)kt + (size_t)it2 * 8 * D, dB + (wid * 32 + it2 * 8) * 64);
    }
  };

  const int nt = D >> 6;
  STAGE(0, 0);
  if (nt > 1){
    STAGE(64, 1);
    asm volatile("s_waitcnt vmcnt(8)" ::: "memory");   // K0 landed, K1 in flight
  } else {
    asm volatile("s_waitcnt vmcnt(0)" ::: "memory");
  }
  __builtin_amdgcn_s_barrier();
  __builtin_amdgcn_sched_barrier(0);

  for (int it = 0; it < nt; ++it){
    const int cur = it & 1;
    const unsigned short* cA = ldsA + cur * (256 * 64);
    const unsigned short* cB = ldsB + cur * (256 * 64);
    // 4 quadrant phases: (mh, nh); each 12 ds_read_b128 + 16 MFMA
    #pragma unroll
    for (int q = 0; q < 4; ++q){
      const int mh = q & 1, nh = q >> 1;
      short8 a[4][2], b[2][2];
      #pragma unroll
      for (int m = 0; m < 4; ++m)
        #pragma unroll
        for (int ks = 0; ks < 2; ++ks){
          int row = wr * 128 + mh * 64 + m * 16 + lr;
          a[m][ks] = *reinterpret_cast<const short8*>(
              &cA[row * 64 + ((ks * 32 + lg * 8) ^ ((row & 7) << 3))]);
        }
      #pragma unroll
      for (int n = 0; n < 2; ++n)
        #pragma unroll
        for (int ks = 0; ks < 2; ++ks){
          int row = wc * 64 + nh * 32 + n * 16 + lr;
          b[n][ks] = *reinterpret_cast<const short8*>(
              &cB[row * 64 + ((ks * 32 + lg * 8) ^ ((row & 7) << 3))]);
        }
      asm volatile("" ::: "memory");
      __builtin_amdgcn_s_barrier();                // phase-align the 8 waves
      __builtin_amdgcn_sched_barrier(0);
      __builtin_amdgcn_s_setprio(1);
      #pragma unroll
      for (int m = 0; m < 4; ++m)
        #pragma unroll
        for (int n = 0; n < 2; ++n)
          #pragma unroll
          for (int ks = 0; ks < 2; ++ks)
            acc[mh * 4 + m][nh * 2 + n] = __builtin_amdgcn_mfma_f32_16x16x32_bf16(
                a[m][ks], b[n][ks], acc[mh * 4 + m][nh * 2 + n], 0, 0, 0);
      __builtin_amdgcn_s_setprio(0);
      __builtin_amdgcn_sched_barrier(0);
    }
    // K-tile boundary: all waves done reading buf[cur]
    asm volatile("" ::: "memory");
    __builtin_amdgcn_s_barrier();
    if (it + 2 < nt){
      STAGE((it + 2) << 6, cur);                   // overwrite cur for K(t+2)
      asm volatile("s_waitcnt vmcnt(8)" ::: "memory");   // K(t+1) landed, K(t+2) flies
      __builtin_amdgcn_s_barrier();
      __builtin_amdgcn_sched_barrier(0);
    } else if (it + 1 < nt){
      asm volatile("s_waitcnt vmcnt(0)" ::: "memory");   // epilogue drain
      __builtin_amdgcn_s_barrier();
      __builtin_amdgcn_sched_barrier(0);
    }
  }

  // epilogue
  const bool docol = (!pdc) && (bx != by);
  int jl[4]; float xj[4], hpj[4];
  #pragma unroll
  for (int an = 0; an < 4; ++an){
    int j = j0 + wc * 64 + (an >> 1) * 32 + (an & 1) * 16 + lr;  // col = lane&15
    jl[an] = pdc ? j : labels[j];
    xj[an] = cxv[j];
    hpj[an] = docol ? hpos[j] : 0.f;
  }
  float cmn[4], cmx[4]; int cfl[4];
  #pragma unroll
  for (int an = 0; an < 4; ++an){ cmn[an] = BIGF; cmx[an] = 0.f; cfl[an] = 0; }

  #pragma unroll
  for (int am = 0; am < 8; ++am){
    #pragma unroll
    for (int r = 0; r < 4; ++r){
      int i = i0 + wr * 128 + (am >> 2) * 64 + (am & 3) * 16 + lg * 4 + r;
      int li = labels[i];
      float xi = exx[i];
      float hpi = hpos[i];
      float mn = BIGF, mx = 0.f; int fl = 0;
      #pragma unroll
      for (int an = 0; an < 4; ++an){
        float d2 = xi + xj[an] - 2.f * acc[am][an][r];
        float d  = sqrtf(fmaxf(d2, EPSC));
        bool an_ = (li != jl[an]);
        bool g  = an_ && (d > hpi);
        mn = fminf(mn, g ? d : BIGF);
        mx = fmaxf(mx, an_ ? d : 0.f);
        fl |= (g ? 1 : 0) | (an_ ? 2 : 0);
        if (docol){
          bool gc = an_ && (d > hpj[an]);
          cmn[an] = fminf(cmn[an], gc ? d : BIGF);
          cmx[an] = fmaxf(cmx[an], an_ ? d : 0.f);
          cfl[an] |= (gc ? 1 : 0) | (an_ ? 2 : 0);
        }
      }
      #pragma unroll
      for (int s = 1; s < 16; s <<= 1){             // reduce across 16 j-lanes
        mn = fminf(mn, __shfl_xor(mn, s));
        mx = fmaxf(mx, __shfl_xor(mx, s));
        fl |= __shfl_xor(fl, s);
      }
      if (lr == 0){
        atomicMin(&mnv[i], __float_as_uint(mn));
        atomicMax(&mxv[i], __float_as_uint(mx));
        if (fl) atomicOr(&flv[i], (unsigned)fl);
      }
    }
  }
  if (docol){
    #pragma unroll
    for (int an = 0; an < 4; ++an){
      float mn = cmn[an], mx = cmx[an]; int fl = cfl[an];
      #pragma unroll
      for (int s = 16; s < 64; s <<= 1){            // reduce across 4 lg groups
        mn = fminf(mn, __shfl_xor(mn, s));
        mx = fmaxf(mx, __shfl_xor(mx, s));
        fl |= __shfl_xor(fl, s);
      }
      if (lg == 0){
        int j = j0 + wc * 64 + (an >> 1) * 32 + (an & 1) * 16 + lr;
        atomicMin(&mn0[j], __float_as_uint(mn));
        atomicMax(&mx0[j], __float_as_uint(mx));
        if (fl) atomicOr(&fl0[j], (unsigned)fl);
      }
    }
  }
}

// ---------------- combine + loss ----------------
__global__ __launch_bounds__(256) void k_final(const float* __restrict__ hpos,
    const unsigned* __restrict__ mn0, const unsigned* __restrict__ mx0,
    const unsigned* __restrict__ fl0, const unsigned* __restrict__ mn1,
    const unsigned* __restrict__ mx1, const unsigned* __restrict__ fl1,
    const float* __restrict__ margin, float* __restrict__ out, int B){
  float part = 0.f;
  float mar = margin[0];
  for (int i = threadIdx.x; i < B; i += blockDim.x){
    float h_out = fminf(__uint_as_float(mn0[i]), __uint_as_float(mn1[i]));
    unsigned f0 = fl0[i], f1 = fl1[i];
    float ni  = (!(f0 & 1u)) ? __uint_as_float(mx0[i]) : ((f0 & 2u) ? BIGF : 0.f);
    float nic = (!(f1 & 1u)) ? __uint_as_float(mx1[i]) : ((f1 & 2u) ? BIGF : 0.f);
    float h_in = fmaxf(ni, nic);
    float hneg = fminf(h_out, h_in);
    float t = hpos[i] - hneg + mar;
    part += fmaxf(t, 0.f);
  }
  float tot = block_reduce_sum(part);
  if (threadIdx.x == 0) out[0] = tot / (float)B;
}

extern "C" void kernel_launch(void* const* d_in, const int* in_sizes, int n_in,
                              void* d_out, int out_size, void* d_ws, size_t ws_size,
                              hipStream_t stream){
  const float* emb    = (const float*)d_in[0];
  const int*   labels = (const int*)d_in[1];
  const float* cval   = (const float*)d_in[2];
  const float* ccnt   = (const float*)d_in[3];
  const float* margin = (const float*)d_in[4];
  float* out = (float*)d_out;

  int B = in_sizes[1];
  int D = in_sizes[0] / B;
  int C = in_sizes[2] / D;
  const int MMAX = 64;

  char* ws = (char*)d_ws;
  size_t off = 0;
  auto alloc = [&](size_t bytes)->char*{
    char* p = ws + off;
    off = (off + bytes + 255) & ~(size_t)255;
    return p;
  };
  unsigned short* enb = (unsigned short*)alloc((size_t)B * D * 2);
  unsigned short* cnb = (unsigned short*)alloc((size_t)C * D * 2);
  float* exx  = (float*)alloc((size_t)B * 4);
  float* cxx  = (float*)alloc((size_t)C * 4);
  float* hpos = (float*)alloc((size_t)B * 4);
  unsigned* mn0 = (unsigned*)alloc((size_t)B * 4);
  unsigned* mx0 = (unsigned*)alloc((size_t)B * 4);
  unsigned* fl0 = (unsigned*)alloc((size_t)B * 4);
  unsigned* mn1 = (unsigned*)alloc((size_t)B * 4);
  unsigned* mx1 = (unsigned*)alloc((size_t)B * 4);
  unsigned* fl1 = (unsigned*)alloc((size_t)B * 4);
  int* cnt     = (int*)alloc((size_t)C * 4);
  int* members = (int*)alloc((size_t)C * MMAX * 4);
  (void)ws_size; (void)n_in; (void)out_size;

  // opt-in to 128KB dynamic LDS for the pd pass (idempotent, capture-safe)
  hipFuncSetAttribute((const void*)k_pd_all,
                      hipFuncAttributeMaxDynamicSharedMemorySize, 131072);

  int mxBC = B > C ? B : C;
  k_setup<<<(mxBC + 255) / 256, 256, (size_t)B * 4, stream>>>(
      labels, cnt, members, mn0, mx0, fl0, mn1, mx1, fl1, B, C, MMAX);

  // prep: norm (B/4 blocks) + centers (C/4 blocks) in one launch
  int nbNorm = B / 4, nbCent = C / 4;
  int R = D >> 9;
  if (R == 4){
    k_prep<4><<<nbNorm + nbCent, 256, 0, stream>>>(emb, cval, ccnt, cnt, members,
                                                   enb, cnb, exx, cxx, D, MMAX, nbNorm);
  } else if (R == 2){
    k_prep<2><<<nbNorm + nbCent, 256, 0, stream>>>(emb, cval, ccnt, cnt, members,
                                                   enb, cnb, exx, cxx, D, MMAX, nbNorm);
  } else {
    k_prep<1><<<nbNorm + nbCent, 256, 0, stream>>>(emb, cval, ccnt, cnt, members,
                                                   enb, cnb, exx, cxx, D, MMAX, nbNorm);
  }

  switch (R){
    case 1: k_hpos<1><<<B/4, 256, 0, stream>>>(enb, cnb, exx, cxx, labels, cnt, members, hpos, D, MMAX); break;
    case 2: k_hpos<2><<<B/4, 256, 0, stream>>>(enb, cnb, exx, cxx, labels, cnt, members, hpos, D, MMAX); break;
    default: k_hpos<4><<<B/4, 256, 0, stream>>>(enb, cnb, exx, cxx, labels, cnt, members, hpos, D, MMAX); break;
  }

  int nby = B / 256, nCx = C / 256;
  int nTri = nby * (nby + 1) / 2;
  k_pd_all<<<nTri + nby * nCx, 512, 131072, stream>>>(
      enb, cnb, exx, cxx, labels, hpos,
      mn0, mx0, fl0, mn1, mx1, fl1, D, nTri, nCx);
  k_final<<<1, 256, 0, stream>>>(hpos, mn0, mx0, fl0, mn1, mx1, fl1, margin, out, B);
}

// Round 7
// 195.322 us; speedup vs baseline: 1.0341x; 1.0341x over previous
//
#include <hip/hip_runtime.h>
#include <hip/hip_bf16.h>

// CaMLoss fused forward for MI355X (gfx950).
// B=4096, D=2048, C=1024. Assumes D%128==0, B%256==0, C%256==0 for the pd pass.
// enb/cnb stored SLOT-SWIZZLED: within each 64-elem chunk of row i, 8-elem slot
// s lives at s ^ (i&7). Linear global_load_lds staging lands swizzled in LDS;
// ds_read at col ^ ((row&7)<<3) is bank-conflict-free (verified: 0 conflicts).
// k_pd_all (R7): faithful half-tile pipeline (HK/m201-derived):
//   - 256^2 tile, BK=64, 8 waves, dbuf x 4 half-slots (16KB) = 128KB LDS
//   - 4 phases per K-tile; phase p=(mh,nh) consumes halves A(mh),B(nh)
//   - each phase stages ONE half of tile t+1 (2 GLL16/wave), order B0,A0,A1,B1
//     -> every half has >=3-phase issue->consume lead
//   - vmcnt(6) gate each phase (last 3 stages allowed in flight; in-order
//     retirement proves the half staged 3 phases ago has landed); tail [4,2,0,0]
//   - one asm-fenced s_barrier per phase; lgkmcnt(0)+sched_barrier before
//     setprio-wrapped 16-MFMA cluster.

typedef __attribute__((ext_vector_type(8))) short short8;
typedef __attribute__((ext_vector_type(4))) float f32x4;

#define BIGF 1e6f
#define EPSC 1e-12f

__device__ __forceinline__ float bf2f(unsigned short u){
  unsigned int x = ((unsigned int)u) << 16;
  return __uint_as_float(x);
}
__device__ __forceinline__ unsigned short f2bf(float f){
  __hip_bfloat16 h = __float2bfloat16(f);
  return *reinterpret_cast<unsigned short*>(&h);
}

__device__ __forceinline__ float block_reduce_sum(float v){
  __shared__ float red[4];
  int tid = threadIdx.x;
  __syncthreads();
  #pragma unroll
  for (int s = 32; s; s >>= 1) v += __shfl_xor(v, s);
  if ((tid & 63) == 0) red[tid >> 6] = v;
  __syncthreads();
  return red[0] + red[1] + red[2] + red[3];
}

// async global->LDS, 16B per lane, wave-uniform LDS base + lane*16
#define GLL16(gptr, lptr) \
  __builtin_amdgcn_global_load_lds( \
      (const __attribute__((address_space(1))) unsigned int*)(gptr), \
      (__attribute__((address_space(3))) unsigned int*)(lptr), 16, 0, 0)

#define VMWAIT(S) asm volatile("s_waitcnt " S ::: "memory")
#define SBAR()    asm volatile("s_barrier" ::: "memory")

// ---------------- setup: init stats + per-class counts + member lists ----------------
__global__ void k_setup(const int* __restrict__ labels, int* cnt, int* members,
                        unsigned* mn0, unsigned* mx0, unsigned* fl0,
                        unsigned* mn1, unsigned* mx1, unsigned* fl1,
                        int B, int C, int MMAX){
  extern __shared__ int slab[];
  for (int j = threadIdx.x; j < B; j += blockDim.x) slab[j] = labels[j];
  __syncthreads();
  int i = blockIdx.x * blockDim.x + threadIdx.x;
  unsigned bigbits = __float_as_uint(BIGF);
  if (i < B){
    mn0[i] = bigbits; mx0[i] = 0u; fl0[i] = 0u;
    mn1[i] = bigbits; mx1[i] = 0u; fl1[i] = 0u;
  }
  if (i < C){
    int c = 0, j = 0;
    int full = B & ~3;
    for (; j < full; j += 4){
      int4 l4 = *reinterpret_cast<const int4*>(&slab[j]);
      c += (l4.x == i) + (l4.y == i) + (l4.z == i) + (l4.w == i);
    }
    for (; j < B; ++j) c += (slab[j] == i);
    cnt[i] = c;
  }
  if (i < B){
    int c = slab[i];
    int rank = 0, j = 0;
    int full = i & ~3;
    for (; j < full; j += 4){
      int4 l4 = *reinterpret_cast<const int4*>(&slab[j]);
      rank += (l4.x == c) + (l4.y == c) + (l4.z == c) + (l4.w == c);
    }
    for (; j < i; ++j) rank += (slab[j] == c);
    if (rank < MMAX) members[c * MMAX + rank] = i;
  }
}

// ---------------- prep: normalize embeddings + centers (merged) ----------------
template<int R>   // R = D/512
__global__ __launch_bounds__(256) void k_prep(const float* __restrict__ emb,
    const float* __restrict__ cval, const float* __restrict__ ccnt,
    const int* __restrict__ cnt, const int* __restrict__ members,
    unsigned short* __restrict__ enb, unsigned short* __restrict__ cnb,
    float* __restrict__ exx, float* __restrict__ cxx,
    int D, int MMAX, int nbNorm){
  int w = threadIdx.x >> 6, lane = threadIdx.x & 63;
  if ((int)blockIdx.x < nbNorm){
    int i = blockIdx.x * 4 + w;
    const float* row = emb + (size_t)i * D;
    float v[R][8];
    float ss = 0.f;
    #pragma unroll
    for (int r = 0; r < R; ++r){
      int base = r * 512 + lane * 8;
      float4 a = *reinterpret_cast<const float4*>(&row[base]);
      float4 b = *reinterpret_cast<const float4*>(&row[base + 4]);
      v[r][0]=a.x; v[r][1]=a.y; v[r][2]=a.z; v[r][3]=a.w;
      v[r][4]=b.x; v[r][5]=b.y; v[r][6]=b.z; v[r][7]=b.w;
      #pragma unroll
      for (int k = 0; k < 8; ++k) ss += v[r][k] * v[r][k];
    }
    #pragma unroll
    for (int s = 1; s < 64; s <<= 1) ss += __shfl_xor(ss, s);
    float inv = 1.f / (sqrtf(ss) + EPSC);
    unsigned short* orow = enb + (size_t)i * D;
    int xr = (i & 7) << 3;
    #pragma unroll
    for (int r = 0; r < R; ++r){
      int base = (r * 512 + lane * 8) ^ xr;
      short8 o;
      #pragma unroll
      for (int k = 0; k < 8; ++k) o[k] = (short)f2bf(v[r][k] * inv);
      *reinterpret_cast<short8*>(&orow[base]) = o;
    }
    if (lane == 0) exx[i] = ss * inv * inv;
  } else {
    int c = ((int)blockIdx.x - nbNorm) * 4 + w;
    int n = cnt[c], m = n < MMAX ? n : MMAX;
    float acc[R][8];
    #pragma unroll
    for (int r = 0; r < R; ++r)
      #pragma unroll
      for (int k = 0; k < 8; ++k) acc[r][k] = 0.f;
    for (int e = 0; e < m; ++e){
      const float* row = emb + (size_t)members[c * MMAX + e] * D;
      #pragma unroll
      for (int r = 0; r < R; ++r){
        int base = r * 512 + lane * 8;
        float4 a = *reinterpret_cast<const float4*>(&row[base]);
        float4 b = *reinterpret_cast<const float4*>(&row[base + 4]);
        acc[r][0]+=a.x; acc[r][1]+=a.y; acc[r][2]+=a.z; acc[r][3]+=a.w;
        acc[r][4]+=b.x; acc[r][5]+=b.y; acc[r][6]+=b.z; acc[r][7]+=b.w;
      }
    }
    float cf = (float)n;
    float ss = 0.f;
    #pragma unroll
    for (int r = 0; r < R; ++r){
      int base = r * 512 + lane * 8;
      float4 u0 = *reinterpret_cast<const float4*>(&ccnt[(size_t)c * D + base]);
      float4 u1 = *reinterpret_cast<const float4*>(&ccnt[(size_t)c * D + base + 4]);
      float4 w0 = *reinterpret_cast<const float4*>(&cval[(size_t)c * D + base]);
      float4 w1 = *reinterpret_cast<const float4*>(&cval[(size_t)c * D + base + 4]);
      float uc[8] = {u0.x,u0.y,u0.z,u0.w,u1.x,u1.y,u1.z,u1.w};
      float wv[8] = {w0.x,w0.y,w0.z,w0.w,w1.x,w1.y,w1.z,w1.w};
      #pragma unroll
      for (int k = 0; k < 8; ++k){
        float u = uc[k] + cf;
        float vv = wv[k] + acc[r][k];
        float ce = (u > 0.f) ? (vv / fmaxf(u, 1.f)) : 0.f;
        acc[r][k] = ce; ss += ce * ce;
      }
    }
    #pragma unroll
    for (int s = 1; s < 64; s <<= 1) ss += __shfl_xor(ss, s);
    float inv = 1.f / (sqrtf(ss) + EPSC);
    int xr = (c & 7) << 3;
    #pragma unroll
    for (int r = 0; r < R; ++r){
      int base = (r * 512 + lane * 8) ^ xr;
      short8 o;
      #pragma unroll
      for (int k = 0; k < 8; ++k) o[k] = (short)f2bf(acc[r][k] * inv);
      *reinterpret_cast<short8*>(&cnb[(size_t)c * D + base]) = o;
    }
    if (lane == 0) cxx[c] = ss * inv * inv;
  }
}

// ---------------- hardest positive: one wave per row ----------------
template<int NCH>
__global__ __launch_bounds__(256) void k_hpos(const unsigned short* __restrict__ enb,
    const unsigned short* __restrict__ cnb, const float* __restrict__ exx,
    const float* __restrict__ cxx, const int* __restrict__ labels,
    const int* __restrict__ cnt, const int* __restrict__ members,
    float* __restrict__ hpos, int D, int MMAX){
  int w = threadIdx.x >> 6, lane = threadIdx.x & 63;
  int i = blockIdx.x * 4 + w;
  int li = labels[i];
  const unsigned short* arow = enb + (size_t)i * D;
  int xri = (i & 7) << 3;
  float av[NCH][8];
  #pragma unroll
  for (int ch = 0; ch < NCH; ++ch){
    short8 a8 = *reinterpret_cast<const short8*>(&arow[(ch * 512 + lane * 8) ^ xri]);
    #pragma unroll
    for (int k = 0; k < 8; ++k) av[ch][k] = bf2f((unsigned short)a8[k]);
  }
  float xi = exx[i];
  float hp = 0.f;
  int m = cnt[li] < MMAX ? cnt[li] : MMAX;
  for (int e = 0; e < m; ++e){
    int j = members[li * MMAX + e];
    if (j == i) continue;                     // wave-uniform
    const unsigned short* brow = enb + (size_t)j * D;
    int xrj = (j & 7) << 3;
    float p = 0.f;
    #pragma unroll
    for (int ch = 0; ch < NCH; ++ch){
      short8 b8 = *reinterpret_cast<const short8*>(&brow[(ch * 512 + lane * 8) ^ xrj]);
      #pragma unroll
      for (int k = 0; k < 8; ++k) p += av[ch][k] * bf2f((unsigned short)b8[k]);
    }
    #pragma unroll
    for (int s = 1; s < 64; s <<= 1) p += __shfl_xor(p, s);
    float d2 = xi + exx[j] - 2.f * p;
    hp = fmaxf(hp, sqrtf(fmaxf(d2, EPSC)));
  }
  {
    const unsigned short* brow = cnb + (size_t)li * D;
    int xrc = (li & 7) << 3;
    float p = 0.f;
    #pragma unroll
    for (int ch = 0; ch < NCH; ++ch){
      short8 b8 = *reinterpret_cast<const short8*>(&brow[(ch * 512 + lane * 8) ^ xrc]);
      #pragma unroll
      for (int k = 0; k < 8; ++k) p += av[ch][k] * bf2f((unsigned short)b8[k]);
    }
    #pragma unroll
    for (int s = 1; s < 64; s <<= 1) p += __shfl_xor(p, s);
    float d2 = xi + cxx[li] - 2.f * p;
    hp = fmaxf(hp, sqrtf(fmaxf(d2, EPSC)));
  }
  if (lane == 0) hpos[i] = hp;
}

// ---------------- merged distance pass: half-tile pipelined 256^2 ----------------
// Stage one half per phase into the OTHER dbuf (fully dead); vmcnt(6) every
// phase; tail tile counts [4,2,0,0].
#define PD_STAGE(SB, KIND, KT) do { \
    unsigned short* dst_ = (SB) + (KIND) * 8192 + wid * (16 * 64); \
    const unsigned short* src_ = ((KIND) < 2 \
        ? gA + (size_t)((KIND) * 128) * D \
        : gB + (size_t)(((KIND) - 2) * 128) * D) + (KT); \
    GLL16(src_, dst_); \
    GLL16(src_ + (size_t)8 * D, dst_ + 8 * 64); \
  } while (0)

#define PD_PHASE(P, VMS, STAGE_CODE) do { \
    STAGE_CODE; \
    VMWAIT(VMS); \
    SBAR(); \
    const unsigned short* hA_ = db + (P & 1) * 8192; \
    const unsigned short* hB_ = db + (2 + (P >> 1)) * 8192; \
    short8 a_[4][2], b_[2][2]; \
    _Pragma("unroll") \
    for (int m_ = 0; m_ < 4; ++m_){ \
      a_[m_][0] = *reinterpret_cast<const short8*>(&hA_[aoff[m_][0]]); \
      a_[m_][1] = *reinterpret_cast<const short8*>(&hA_[aoff[m_][1]]); \
    } \
    _Pragma("unroll") \
    for (int n_ = 0; n_ < 2; ++n_){ \
      b_[n_][0] = *reinterpret_cast<const short8*>(&hB_[boff[n_][0]]); \
      b_[n_][1] = *reinterpret_cast<const short8*>(&hB_[boff[n_][1]]); \
    } \
    VMWAIT("lgkmcnt(0)"); \
    __builtin_amdgcn_sched_barrier(0); \
    __builtin_amdgcn_s_setprio(1); \
    _Pragma("unroll") \
    for (int m_ = 0; m_ < 4; ++m_) \
      _Pragma("unroll") \
      for (int n_ = 0; n_ < 2; ++n_) \
        _Pragma("unroll") \
        for (int ks_ = 0; ks_ < 2; ++ks_) \
          acc[P & 1][P >> 1][m_][n_] = __builtin_amdgcn_mfma_f32_16x16x32_bf16( \
              a_[m_][ks_], b_[n_][ks_], acc[P & 1][P >> 1][m_][n_], 0, 0, 0); \
    __builtin_amdgcn_s_setprio(0); \
  } while (0)

__global__ __launch_bounds__(512, 2) void k_pd_all(
    const unsigned short* __restrict__ enb,
    const unsigned short* __restrict__ cnb,
    const float* __restrict__ exx, const float* __restrict__ cxx,
    const int* __restrict__ labels, const float* __restrict__ hpos,
    unsigned* __restrict__ mn0, unsigned* __restrict__ mx0, unsigned* __restrict__ fl0,
    unsigned* __restrict__ mn1, unsigned* __restrict__ mx1, unsigned* __restrict__ fl1,
    int D, int nTri, int nCx)
{
  extern __shared__ unsigned short sm[];           // 8 half-slots x 16KB = 128KB
  // bijective XCD swizzle (m204)
  const int nwg = gridDim.x;
  const int orig = blockIdx.x;
  const int q8 = nwg >> 3, r8 = nwg & 7;
  const int xcd = orig & 7, idx = orig >> 3;
  const int t = (xcd < r8 ? xcd * (q8 + 1) : r8 * (q8 + 1) + (xcd - r8) * q8) + idx;

  const bool pdc = (t >= nTri);
  int bx, by;
  if (!pdc){
    int b = (int)((sqrtf(8.f * (float)t + 1.f) - 1.f) * 0.5f);
    while ((b + 1) * (b + 2) / 2 <= t) ++b;
    while (b * (b + 1) / 2 > t) --b;
    by = b; bx = t - b * (b + 1) / 2;              // bx <= by
  } else {
    int u = t - nTri;
    by = u / nCx; bx = u - by * nCx;
  }
  const unsigned short* cmat = pdc ? cnb : enb;
  const float* cxv = pdc ? cxx : exx;
  unsigned* mnv = pdc ? mn1 : mn0;
  unsigned* mxv = pdc ? mx1 : mx0;
  unsigned* flv = pdc ? fl1 : fl0;

  const int j0 = bx * 256, i0 = by * 256;
  const int tid = threadIdx.x;
  const int wid = tid >> 6, lane = tid & 63;
  const int wr = wid >> 2, wc = wid & 3;           // quadrant row/col bands
  const int lr = lane & 15, lg = lane >> 4;

  // stage source per-lane bases: wave wid stages rows [wid*16, wid*16+16) of a half
  const int srow = wid * 16 + (lane >> 3);
  const int scol = (lane & 7) * 8;
  const unsigned short* gA = enb  + (size_t)(i0 + srow) * D + scol;
  const unsigned short* gB = cmat + (size_t)(j0 + srow) * D + scol;

  // ds_read offsets (within a 16KB half laid out [128][64], swizzled)
  int aoff[4][2], boff[2][2];
  #pragma unroll
  for (int m = 0; m < 4; ++m){
    int ra = wr * 64 + m * 16 + lr;
    #pragma unroll
    for (int ks = 0; ks < 2; ++ks)
      aoff[m][ks] = ra * 64 + ((ks * 32 + lg * 8) ^ ((ra & 7) << 3));
  }
  #pragma unroll
  for (int n = 0; n < 2; ++n){
    int rb = wc * 32 + n * 16 + lr;
    #pragma unroll
    for (int ks = 0; ks < 2; ++ks)
      boff[n][ks] = rb * 64 + ((ks * 32 + lg * 8) ^ ((rb & 7) << 3));
  }

  f32x4 acc[2][2][4][2];
  #pragma unroll
  for (int mh = 0; mh < 2; ++mh)
    #pragma unroll
    for (int nh = 0; nh < 2; ++nh)
      #pragma unroll
      for (int m = 0; m < 4; ++m)
        #pragma unroll
        for (int n = 0; n < 2; ++n)
          acc[mh][nh][m][n] = (f32x4){0.f, 0.f, 0.f, 0.f};

  const int nt = D >> 6;
  // prologue: stage all 4 halves of tile 0 into dbuf 0, drain once
  PD_STAGE(sm, 0, 0); PD_STAGE(sm, 1, 0); PD_STAGE(sm, 2, 0); PD_STAGE(sm, 3, 0);
  VMWAIT("vmcnt(0)");
  SBAR();

  for (int it = 0; it < nt - 1; ++it){
    const unsigned short* db = sm + (size_t)(it & 1) * (4 * 8192);
    unsigned short* sb = sm + (size_t)((it & 1) ^ 1) * (4 * 8192);
    const int ktn = (it + 1) << 6;
    PD_PHASE(0, "vmcnt(6)", PD_STAGE(sb, 2, ktn));   // stage B0' (lead 4)
    PD_PHASE(1, "vmcnt(6)", PD_STAGE(sb, 0, ktn));   // stage A0' (lead 3)
    PD_PHASE(2, "vmcnt(6)", PD_STAGE(sb, 1, ktn));   // stage A1' (lead 3)
    PD_PHASE(3, "vmcnt(6)", PD_STAGE(sb, 3, ktn));   // stage B1' (lead 3)
  }
  { // tail tile: no staging, counted drain
    const unsigned short* db = sm + (size_t)((nt - 1) & 1) * (4 * 8192);
    PD_PHASE(0, "vmcnt(4)", (void)0);
    PD_PHASE(1, "vmcnt(2)", (void)0);
    PD_PHASE(2, "vmcnt(0)", (void)0);
    PD_PHASE(3, "vmcnt(0)", (void)0);
  }

  // epilogue: rows i = i0 + mh*128 + wr*64 + m*16 + lg*4 + r
  //           cols j = j0 + nh*128 + wc*32 + n*16 + lr
  const bool docol = (!pdc) && (bx != by);
  int jl[2][2]; float xj[2][2], hpj[2][2];
  #pragma unroll
  for (int nh = 0; nh < 2; ++nh)
    #pragma unroll
    for (int n = 0; n < 2; ++n){
      int j = j0 + nh * 128 + wc * 32 + n * 16 + lr;
      jl[nh][n] = pdc ? j : labels[j];
      xj[nh][n] = cxv[j];
      hpj[nh][n] = docol ? hpos[j] : 0.f;
    }
  float cmn[2][2], cmx[2][2]; int cfl[2][2];
  #pragma unroll
  for (int nh = 0; nh < 2; ++nh)
    #pragma unroll
    for (int n = 0; n < 2; ++n){ cmn[nh][n] = BIGF; cmx[nh][n] = 0.f; cfl[nh][n] = 0; }

  #pragma unroll
  for (int mh = 0; mh < 2; ++mh)
    #pragma unroll
    for (int m = 0; m < 4; ++m)
      #pragma unroll
      for (int r = 0; r < 4; ++r){
        int i = i0 + mh * 128 + wr * 64 + m * 16 + lg * 4 + r;
        int li = labels[i];
        float xi = exx[i];
        float hpi = hpos[i];
        float mn = BIGF, mx = 0.f; int fl = 0;
        #pragma unroll
        for (int nh = 0; nh < 2; ++nh)
          #pragma unroll
          for (int n = 0; n < 2; ++n){
            float d2 = xi + xj[nh][n] - 2.f * acc[mh][nh][m][n][r];
            float d  = sqrtf(fmaxf(d2, EPSC));
            bool an = (li != jl[nh][n]);
            bool g  = an && (d > hpi);
            mn = fminf(mn, g ? d : BIGF);
            mx = fmaxf(mx, an ? d : 0.f);
            fl |= (g ? 1 : 0) | (an ? 2 : 0);
            if (docol){
              bool gc = an && (d > hpj[nh][n]);
              cmn[nh][n] = fminf(cmn[nh][n], gc ? d : BIGF);
              cmx[nh][n] = fmaxf(cmx[nh][n], an ? d : 0.f);
              cfl[nh][n] |= (gc ? 1 : 0) | (an ? 2 : 0);
            }
          }
        #pragma unroll
        for (int s = 1; s < 16; s <<= 1){             // reduce across 16 j-lanes
          mn = fminf(mn, __shfl_xor(mn, s));
          mx = fmaxf(mx, __shfl_xor(mx, s));
          fl |= __shfl_xor(fl, s);
        }
        if (lr == 0){
          atomicMin(&mnv[i], __float_as_uint(mn));
          atomicMax(&mxv[i], __float_as_uint(mx));
          if (fl) atomicOr(&flv[i], (unsigned)fl);
        }
      }
  if (docol){
    #pragma unroll
    for (int nh = 0; nh < 2; ++nh)
      #pragma unroll
      for (int n = 0; n < 2; ++n){
        float mn = cmn[nh][n], mx = cmx[nh][n]; int fl = cfl[nh][n];
        #pragma unroll
        for (int s = 16; s < 64; s <<= 1){            // reduce across 4 lg groups
          mn = fminf(mn, __shfl_xor(mn, s));
          mx = fmaxf(mx, __shfl_xor(mx, s));
          fl |= __shfl_xor(fl, s);
        }
        if (lg == 0){
          int j = j0 + nh * 128 + wc * 32 + n * 16 + lr;
          atomicMin(&mn0[j], __float_as_uint(mn));
          atomicMax(&mx0[j], __float_as_uint(mx));
          if (fl) atomicOr(&fl0[j], (unsigned)fl);
        }
      }
  }
}

// ---------------- combine + loss ----------------
__global__ __launch_bounds__(256) void k_final(const float* __restrict__ hpos,
    const unsigned* __restrict__ mn0, const unsigned* __restrict__ mx0,
    const unsigned* __restrict__ fl0, const unsigned* __restrict__ mn1,
    const unsigned* __restrict__ mx1, const unsigned* __restrict__ fl1,
    const float* __restrict__ margin, float* __restrict__ out, int B){
  float part = 0.f;
  float mar = margin[0];
  for (int i = threadIdx.x; i < B; i += blockDim.x){
    float h_out = fminf(__uint_as_float(mn0[i]), __uint_as_float(mn1[i]));
    unsigned f0 = fl0[i], f1 = fl1[i];
    float ni  = (!(f0 & 1u)) ? __uint_as_float(mx0[i]) : ((f0 & 2u) ? BIGF : 0.f);
    float nic = (!(f1 & 1u)) ? __uint_as_float(mx1[i]) : ((f1 & 2u) ? BIGF : 0.f);
    float h_in = fmaxf(ni, nic);
    float hneg = fminf(h_out, h_in);
    float t = hpos[i] - hneg + mar;
    part += fmaxf(t, 0.f);
  }
  float tot = block_reduce_sum(part);
  if (threadIdx.x == 0) out[0] = tot / (float)B;
}

extern "C" void kernel_launch(void* const* d_in, const int* in_sizes, int n_in,
                              void* d_out, int out_size, void* d_ws, size_t ws_size,
                              hipStream_t stream){
  const float* emb    = (const float*)d_in[0];
  const int*   labels = (const int*)d_in[1];
  const float* cval   = (const float*)d_in[2];
  const float* ccnt   = (const float*)d_in[3];
  const float* margin = (const float*)d_in[4];
  float* out = (float*)d_out;

  int B = in_sizes[1];
  int D = in_sizes[0] / B;
  int C = in_sizes[2] / D;
  const int MMAX = 64;

  char* ws = (char*)d_ws;
  size_t off = 0;
  auto alloc = [&](size_t bytes)->char*{
    char* p = ws + off;
    off = (off + bytes + 255) & ~(size_t)255;
    return p;
  };
  unsigned short* enb = (unsigned short*)alloc((size_t)B * D * 2);
  unsigned short* cnb = (unsigned short*)alloc((size_t)C * D * 2);
  float* exx  = (float*)alloc((size_t)B * 4);
  float* cxx  = (float*)alloc((size_t)C * 4);
  float* hpos = (float*)alloc((size_t)B * 4);
  unsigned* mn0 = (unsigned*)alloc((size_t)B * 4);
  unsigned* mx0 = (unsigned*)alloc((size_t)B * 4);
  unsigned* fl0 = (unsigned*)alloc((size_t)B * 4);
  unsigned* mn1 = (unsigned*)alloc((size_t)B * 4);
  unsigned* mx1 = (unsigned*)alloc((size_t)B * 4);
  unsigned* fl1 = (unsigned*)alloc((size_t)B * 4);
  int* cnt     = (int*)alloc((size_t)C * 4);
  int* members = (int*)alloc((size_t)C * MMAX * 4);
  (void)ws_size; (void)n_in; (void)out_size;

  hipFuncSetAttribute((const void*)k_pd_all,
                      hipFuncAttributeMaxDynamicSharedMemorySize, 131072);

  int mxBC = B > C ? B : C;
  k_setup<<<(mxBC + 255) / 256, 256, (size_t)B * 4, stream>>>(
      labels, cnt, members, mn0, mx0, fl0, mn1, mx1, fl1, B, C, MMAX);

  int nbNorm = B / 4, nbCent = C / 4;
  int R = D >> 9;
  if (R == 4){
    k_prep<4><<<nbNorm + nbCent, 256, 0, stream>>>(emb, cval, ccnt, cnt, members,
                                                   enb, cnb, exx, cxx, D, MMAX, nbNorm);
  } else if (R == 2){
    k_prep<2><<<nbNorm + nbCent, 256, 0, stream>>>(emb, cval, ccnt, cnt, members,
                                                   enb, cnb, exx, cxx, D, MMAX, nbNorm);
  } else {
    k_prep<1><<<nbNorm + nbCent, 256, 0, stream>>>(emb, cval, ccnt, cnt, members,
                                                   enb, cnb, exx, cxx, D, MMAX, nbNorm);
  }

  switch (R){
    case 1: k_hpos<1><<<B/4, 256, 0, stream>>>(enb, cnb, exx, cxx, labels, cnt, members, hpos, D, MMAX); break;
    case 2: k_hpos<2><<<B/4, 256, 0, stream>>>(enb, cnb, exx, cxx, labels, cnt, members, hpos, D, MMAX); break;
    default: k_hpos<4><<<B/4, 256, 0, stream>>>(enb, cnb, exx, cxx, labels, cnt, members, hpos, D, MMAX); break;
  }

  int nby = B / 256, nCx = C / 256;
  int nTri = nby * (nby + 1) / 2;
  k_pd_all<<<nTri + nby * nCx, 512, 131072, stream>>>(
      enb, cnb, exx, cxx, labels, hpos,
      mn0, mx0, fl0, mn1, mx1, fl1, D, nTri, nCx);
  k_final<<<1, 256, 0, stream>>>(hpos, mn0, mx0, fl0, mn1, mx1, fl1, margin, out, B);
}

// Round 8
// 156.426 us; speedup vs baseline: 1.2913x; 1.2487x over previous
//
#include <hip/hip_runtime.h>
#include <hip/hip_bf16.h>

// CaMLoss fused forward for MI355X (gfx950).
// B=4096, D=2048, C=1024. Assumes D%512==0 (R in {1,2,4}), B%256==0, C%256==0.
// enb/cnb stored SLOT-SWIZZLED: within each 64-elem chunk of row i, 8-elem slot
// s lives at s ^ (i&7); ds_read at col ^ ((row&7)<<3) is conflict-free (verified 0).
// k_pd_all (R8): half-tile pipeline with OPERAND RETENTION (minimal LDS reads):
//   A0,A1 held in registers across the K-tile; B persistent over 2 phases.
//   Phase order (A0,B0),(A1,B0),(A1,B1),(A0,B1); reads 12/8/4/0 = 24 per tile
//   per wave (the minimum). Stage 1 half per phase, vmcnt(6) gates, tail [4,2,0,-].
// LDS-BW model: reads 192KB + writes 64KB per CU per K-tile ~= 3000cyc vs MFMA 2480.

typedef __attribute__((ext_vector_type(8))) short short8;
typedef __attribute__((ext_vector_type(4))) float f32x4;

#define BIGF 1e6f
#define EPSC 1e-12f

__device__ __forceinline__ float bf2f(unsigned short u){
  unsigned int x = ((unsigned int)u) << 16;
  return __uint_as_float(x);
}
__device__ __forceinline__ unsigned short f2bf(float f){
  __hip_bfloat16 h = __float2bfloat16(f);
  return *reinterpret_cast<unsigned short*>(&h);
}

__device__ __forceinline__ float block_reduce_sum(float v){
  __shared__ float red[4];
  int tid = threadIdx.x;
  __syncthreads();
  #pragma unroll
  for (int s = 32; s; s >>= 1) v += __shfl_xor(v, s);
  if ((tid & 63) == 0) red[tid >> 6] = v;
  __syncthreads();
  return red[0] + red[1] + red[2] + red[3];
}

// async global->LDS, 16B per lane, wave-uniform LDS base + lane*16
#define GLL16(gptr, lptr) \
  __builtin_amdgcn_global_load_lds( \
      (const __attribute__((address_space(1))) unsigned int*)(gptr), \
      (__attribute__((address_space(3))) unsigned int*)(lptr), 16, 0, 0)

#define VMWAIT(S) asm volatile("s_waitcnt " S ::: "memory")
#define SBAR()    asm volatile("s_barrier" ::: "memory")

// ---------------- setup: init stats + ballot-based per-class member lists ----------------
// One wave per class: scan labels in 64-chunks, ballot+popc prefix -> rank order
// (ascending index, deterministic). cnt[c] = total count.
__global__ __launch_bounds__(256) void k_setup(const int* __restrict__ labels,
    int* cnt, int* members,
    unsigned* mn0, unsigned* mx0, unsigned* fl0,
    unsigned* mn1, unsigned* mx1, unsigned* fl1,
    int B, int C, int MMAX){
  int gid = blockIdx.x * blockDim.x + threadIdx.x;
  unsigned bigbits = __float_as_uint(BIGF);
  if (gid < B){
    mn0[gid] = bigbits; mx0[gid] = 0u; fl0[gid] = 0u;
    mn1[gid] = bigbits; mx1[gid] = 0u; fl1[gid] = 0u;
  }
  int w = threadIdx.x >> 6, lane = threadIdx.x & 63;
  int c = blockIdx.x * 4 + w;
  if (c >= C) return;                       // wave-uniform
  int base = 0;
  int nit = (B + 63) >> 6;
  for (int itc = 0; itc < nit; ++itc){
    int idx = itc * 64 + lane;
    int lab = (idx < B) ? labels[idx] : -1;
    unsigned long long m = __ballot(lab == c);
    if (lab == c){
      int rk = base + (int)__popcll(m & ((1ull << lane) - 1ull));
      if (rk < MMAX) members[c * MMAX + rk] = idx;
    }
    base += (int)__popcll(m);
  }
  if (lane == 0) cnt[c] = base;
}

// ---------------- prep: normalize embeddings + centers (merged) ----------------
template<int R>   // R = D/512
__global__ __launch_bounds__(256) void k_prep(const float* __restrict__ emb,
    const float* __restrict__ cval, const float* __restrict__ ccnt,
    const int* __restrict__ cnt, const int* __restrict__ members,
    unsigned short* __restrict__ enb, unsigned short* __restrict__ cnb,
    float* __restrict__ exx, float* __restrict__ cxx,
    int D, int MMAX, int nbNorm){
  int w = threadIdx.x >> 6, lane = threadIdx.x & 63;
  if ((int)blockIdx.x < nbNorm){
    int i = blockIdx.x * 4 + w;
    const float* row = emb + (size_t)i * D;
    float v[R][8];
    float ss = 0.f;
    #pragma unroll
    for (int r = 0; r < R; ++r){
      int base = r * 512 + lane * 8;
      float4 a = *reinterpret_cast<const float4*>(&row[base]);
      float4 b = *reinterpret_cast<const float4*>(&row[base + 4]);
      v[r][0]=a.x; v[r][1]=a.y; v[r][2]=a.z; v[r][3]=a.w;
      v[r][4]=b.x; v[r][5]=b.y; v[r][6]=b.z; v[r][7]=b.w;
      #pragma unroll
      for (int k = 0; k < 8; ++k) ss += v[r][k] * v[r][k];
    }
    #pragma unroll
    for (int s = 1; s < 64; s <<= 1) ss += __shfl_xor(ss, s);
    float inv = 1.f / (sqrtf(ss) + EPSC);
    unsigned short* orow = enb + (size_t)i * D;
    int xr = (i & 7) << 3;
    #pragma unroll
    for (int r = 0; r < R; ++r){
      int base = (r * 512 + lane * 8) ^ xr;
      short8 o;
      #pragma unroll
      for (int k = 0; k < 8; ++k) o[k] = (short)f2bf(v[r][k] * inv);
      *reinterpret_cast<short8*>(&orow[base]) = o;
    }
    if (lane == 0) exx[i] = ss * inv * inv;
  } else {
    int c = ((int)blockIdx.x - nbNorm) * 4 + w;
    int n = cnt[c], m = n < MMAX ? n : MMAX;
    float acc[R][8];
    #pragma unroll
    for (int r = 0; r < R; ++r)
      #pragma unroll
      for (int k = 0; k < 8; ++k) acc[r][k] = 0.f;
    for (int e = 0; e < m; ++e){
      const float* row = emb + (size_t)members[c * MMAX + e] * D;
      #pragma unroll
      for (int r = 0; r < R; ++r){
        int base = r * 512 + lane * 8;
        float4 a = *reinterpret_cast<const float4*>(&row[base]);
        float4 b = *reinterpret_cast<const float4*>(&row[base + 4]);
        acc[r][0]+=a.x; acc[r][1]+=a.y; acc[r][2]+=a.z; acc[r][3]+=a.w;
        acc[r][4]+=b.x; acc[r][5]+=b.y; acc[r][6]+=b.z; acc[r][7]+=b.w;
      }
    }
    float cf = (float)n;
    float ss = 0.f;
    #pragma unroll
    for (int r = 0; r < R; ++r){
      int base = r * 512 + lane * 8;
      float4 u0 = *reinterpret_cast<const float4*>(&ccnt[(size_t)c * D + base]);
      float4 u1 = *reinterpret_cast<const float4*>(&ccnt[(size_t)c * D + base + 4]);
      float4 w0 = *reinterpret_cast<const float4*>(&cval[(size_t)c * D + base]);
      float4 w1 = *reinterpret_cast<const float4*>(&cval[(size_t)c * D + base + 4]);
      float uc[8] = {u0.x,u0.y,u0.z,u0.w,u1.x,u1.y,u1.z,u1.w};
      float wv[8] = {w0.x,w0.y,w0.z,w0.w,w1.x,w1.y,w1.z,w1.w};
      #pragma unroll
      for (int k = 0; k < 8; ++k){
        float u = uc[k] + cf;
        float vv = wv[k] + acc[r][k];
        float ce = (u > 0.f) ? (vv / fmaxf(u, 1.f)) : 0.f;
        acc[r][k] = ce; ss += ce * ce;
      }
    }
    #pragma unroll
    for (int s = 1; s < 64; s <<= 1) ss += __shfl_xor(ss, s);
    float inv = 1.f / (sqrtf(ss) + EPSC);
    int xr = (c & 7) << 3;
    #pragma unroll
    for (int r = 0; r < R; ++r){
      int base = (r * 512 + lane * 8) ^ xr;
      short8 o;
      #pragma unroll
      for (int k = 0; k < 8; ++k) o[k] = (short)f2bf(acc[r][k] * inv);
      *reinterpret_cast<short8*>(&cnb[(size_t)c * D + base]) = o;
    }
    if (lane == 0) cxx[c] = ss * inv * inv;
  }
}

// ---------------- hardest positive: one wave per row ----------------
template<int NCH>
__global__ __launch_bounds__(256) void k_hpos(const unsigned short* __restrict__ enb,
    const unsigned short* __restrict__ cnb, const float* __restrict__ exx,
    const float* __restrict__ cxx, const int* __restrict__ labels,
    const int* __restrict__ cnt, const int* __restrict__ members,
    float* __restrict__ hpos, int D, int MMAX){
  int w = threadIdx.x >> 6, lane = threadIdx.x & 63;
  int i = blockIdx.x * 4 + w;
  int li = labels[i];
  const unsigned short* arow = enb + (size_t)i * D;
  int xri = (i & 7) << 3;
  float av[NCH][8];
  #pragma unroll
  for (int ch = 0; ch < NCH; ++ch){
    short8 a8 = *reinterpret_cast<const short8*>(&arow[(ch * 512 + lane * 8) ^ xri]);
    #pragma unroll
    for (int k = 0; k < 8; ++k) av[ch][k] = bf2f((unsigned short)a8[k]);
  }
  float xi = exx[i];
  float hp = 0.f;
  int m = cnt[li] < MMAX ? cnt[li] : MMAX;
  for (int e = 0; e < m; ++e){
    int j = members[li * MMAX + e];
    if (j == i) continue;                     // wave-uniform
    const unsigned short* brow = enb + (size_t)j * D;
    int xrj = (j & 7) << 3;
    float p = 0.f;
    #pragma unroll
    for (int ch = 0; ch < NCH; ++ch){
      short8 b8 = *reinterpret_cast<const short8*>(&brow[(ch * 512 + lane * 8) ^ xrj]);
      #pragma unroll
      for (int k = 0; k < 8; ++k) p += av[ch][k] * bf2f((unsigned short)b8[k]);
    }
    #pragma unroll
    for (int s = 1; s < 64; s <<= 1) p += __shfl_xor(p, s);
    float d2 = xi + exx[j] - 2.f * p;
    hp = fmaxf(hp, sqrtf(fmaxf(d2, EPSC)));
  }
  {
    const unsigned short* brow = cnb + (size_t)li * D;
    int xrc = (li & 7) << 3;
    float p = 0.f;
    #pragma unroll
    for (int ch = 0; ch < NCH; ++ch){
      short8 b8 = *reinterpret_cast<const short8*>(&brow[(ch * 512 + lane * 8) ^ xrc]);
      #pragma unroll
      for (int k = 0; k < 8; ++k) p += av[ch][k] * bf2f((unsigned short)b8[k]);
    }
    #pragma unroll
    for (int s = 1; s < 64; s <<= 1) p += __shfl_xor(p, s);
    float d2 = xi + cxx[li] - 2.f * p;
    hp = fmaxf(hp, sqrtf(fmaxf(d2, EPSC)));
  }
  if (lane == 0) hpos[i] = hp;
}

// ---------------- merged distance pass: retention half-tile pipelined 256^2 ----------------
#define PD_STAGE(SB, KIND, KT) do { \
    unsigned short* dst_ = (SB) + (KIND) * 8192 + wid * (16 * 64); \
    const unsigned short* src_ = ((KIND) < 2 \
        ? gA + (size_t)((KIND) * 128) * D \
        : gB + (size_t)(((KIND) - 2) * 128) * D) + (KT); \
    GLL16(src_, dst_); \
    GLL16(src_ + (size_t)8 * D, dst_ + 8 * 64); \
  } while (0)

#define RD_A(DST, HP) do { \
    _Pragma("unroll") \
    for (int m_ = 0; m_ < 4; ++m_){ \
      DST[m_][0] = *reinterpret_cast<const short8*>(&(HP)[aoff[m_][0]]); \
      DST[m_][1] = *reinterpret_cast<const short8*>(&(HP)[aoff[m_][1]]); \
    } } while (0)

#define RD_B(HP) do { \
    _Pragma("unroll") \
    for (int n_ = 0; n_ < 2; ++n_){ \
      b[n_][0] = *reinterpret_cast<const short8*>(&(HP)[boff[n_][0]]); \
      b[n_][1] = *reinterpret_cast<const short8*>(&(HP)[boff[n_][1]]); \
    } } while (0)

#define LGKM0() do { VMWAIT("lgkmcnt(0)"); __builtin_amdgcn_sched_barrier(0); } while (0)

#define MFMA16(AV, MH, NH) do { \
    __builtin_amdgcn_s_setprio(1); \
    _Pragma("unroll") \
    for (int m_ = 0; m_ < 4; ++m_) \
      _Pragma("unroll") \
      for (int n_ = 0; n_ < 2; ++n_) \
        _Pragma("unroll") \
        for (int ks_ = 0; ks_ < 2; ++ks_) \
          acc[MH][NH][m_][n_] = __builtin_amdgcn_mfma_f32_16x16x32_bf16( \
              AV[m_][ks_], b[n_][ks_], acc[MH][NH][m_][n_], 0, 0, 0); \
    __builtin_amdgcn_s_setprio(0); } while (0)

__global__ __launch_bounds__(512, 2) void k_pd_all(
    const unsigned short* __restrict__ enb,
    const unsigned short* __restrict__ cnb,
    const float* __restrict__ exx, const float* __restrict__ cxx,
    const int* __restrict__ labels, const float* __restrict__ hpos,
    unsigned* __restrict__ mn0, unsigned* __restrict__ mx0, unsigned* __restrict__ fl0,
    unsigned* __restrict__ mn1, unsigned* __restrict__ mx1, unsigned* __restrict__ fl1,
    int D, int nTri, int nCx)
{
  extern __shared__ unsigned short sm[];           // 2 dbuf x 4 half-slots x 16KB = 128KB
  // bijective XCD swizzle (m204)
  const int nwg = gridDim.x;
  const int orig = blockIdx.x;
  const int q8 = nwg >> 3, r8 = nwg & 7;
  const int xcd = orig & 7, idx = orig >> 3;
  const int t = (xcd < r8 ? xcd * (q8 + 1) : r8 * (q8 + 1) + (xcd - r8) * q8) + idx;

  const bool pdc = (t >= nTri);
  int bx, by;
  if (!pdc){
    int b_ = (int)((sqrtf(8.f * (float)t + 1.f) - 1.f) * 0.5f);
    while ((b_ + 1) * (b_ + 2) / 2 <= t) ++b_;
    while (b_ * (b_ + 1) / 2 > t) --b_;
    by = b_; bx = t - b_ * (b_ + 1) / 2;           // bx <= by
  } else {
    int u = t - nTri;
    by = u / nCx; bx = u - by * nCx;
  }
  const unsigned short* cmat = pdc ? cnb : enb;
  const float* cxv = pdc ? cxx : exx;
  unsigned* mnv = pdc ? mn1 : mn0;
  unsigned* mxv = pdc ? mx1 : mx0;
  unsigned* flv = pdc ? fl1 : fl0;

  const int j0 = bx * 256, i0 = by * 256;
  const int tid = threadIdx.x;
  const int wid = tid >> 6, lane = tid & 63;
  const int wr = wid >> 2, wc = wid & 3;           // 2M x 4N wave bands
  const int lr = lane & 15, lg = lane >> 4;

  // stage source: wave wid stages rows [wid*16, wid*16+16) of each half
  const int srow = wid * 16 + (lane >> 3);
  const int scol = (lane & 7) * 8;
  const unsigned short* gA = enb  + (size_t)(i0 + srow) * D + scol;
  const unsigned short* gB = cmat + (size_t)(j0 + srow) * D + scol;

  // ds_read offsets within a 16KB half [128][64] (swizzled)
  int aoff[4][2], boff[2][2];
  #pragma unroll
  for (int m = 0; m < 4; ++m){
    int ra = wr * 64 + m * 16 + lr;
    #pragma unroll
    for (int ks = 0; ks < 2; ++ks)
      aoff[m][ks] = ra * 64 + ((ks * 32 + lg * 8) ^ ((ra & 7) << 3));
  }
  #pragma unroll
  for (int n = 0; n < 2; ++n){
    int rb = wc * 32 + n * 16 + lr;
    #pragma unroll
    for (int ks = 0; ks < 2; ++ks)
      boff[n][ks] = rb * 64 + ((ks * 32 + lg * 8) ^ ((rb & 7) << 3));
  }

  f32x4 acc[2][2][4][2];
  #pragma unroll
  for (int mh = 0; mh < 2; ++mh)
    #pragma unroll
    for (int nh = 0; nh < 2; ++nh)
      #pragma unroll
      for (int m = 0; m < 4; ++m)
        #pragma unroll
        for (int n = 0; n < 2; ++n)
          acc[mh][nh][m][n] = (f32x4){0.f, 0.f, 0.f, 0.f};

  short8 a0[4][2], a1[4][2], b[2][2];

  const int nt = D >> 6;
  // prologue: stage all 4 halves of tile 0, drain once
  PD_STAGE(sm, 0, 0); PD_STAGE(sm, 1, 0); PD_STAGE(sm, 2, 0); PD_STAGE(sm, 3, 0);
  VMWAIT("vmcnt(0)");
  SBAR();

  for (int it = 0; it < nt; ++it){
    const unsigned short* db = sm + (size_t)(it & 1) * 32768;
    unsigned short* sb = sm + (size_t)((it & 1) ^ 1) * 32768;
    const bool hn = (it + 1 < nt);
    const int ktn = (it + 1) << 6;
    // phase 0: consume (A0,B0); stage B0'
    if (hn){ PD_STAGE(sb, 2, ktn); VMWAIT("vmcnt(6)"); } else { VMWAIT("vmcnt(4)"); }
    SBAR();
    RD_A(a0, db);
    RD_B(db + 2 * 8192);
    LGKM0();
    MFMA16(a0, 0, 0);
    // phase 1: consume (A1,B0); stage A0'
    if (hn){ PD_STAGE(sb, 0, ktn); VMWAIT("vmcnt(6)"); } else { VMWAIT("vmcnt(2)"); }
    SBAR();
    RD_A(a1, db + 1 * 8192);
    LGKM0();
    MFMA16(a1, 1, 0);
    // phase 2: consume (A1,B1); stage A1'
    if (hn){ PD_STAGE(sb, 1, ktn); VMWAIT("vmcnt(6)"); } else { VMWAIT("vmcnt(0)"); }
    SBAR();
    RD_B(db + 3 * 8192);
    LGKM0();
    MFMA16(a1, 1, 1);
    // phase 3: consume (A0,B1) from registers; stage B1'
    if (hn){ PD_STAGE(sb, 3, ktn); VMWAIT("vmcnt(6)"); }
    SBAR();
    MFMA16(a0, 0, 1);
  }

  // epilogue: rows i = i0 + mh*128 + wr*64 + m*16 + lg*4 + r
  //           cols j = j0 + nh*128 + wc*32 + n*16 + lr
  const bool docol = (!pdc) && (bx != by);
  int jl[2][2]; float xj[2][2], hpj[2][2];
  #pragma unroll
  for (int nh = 0; nh < 2; ++nh)
    #pragma unroll
    for (int n = 0; n < 2; ++n){
      int j = j0 + nh * 128 + wc * 32 + n * 16 + lr;
      jl[nh][n] = pdc ? j : labels[j];
      xj[nh][n] = cxv[j];
      hpj[nh][n] = docol ? hpos[j] : 0.f;
    }
  float cmn[2][2], cmx[2][2]; int cfl[2][2];
  #pragma unroll
  for (int nh = 0; nh < 2; ++nh)
    #pragma unroll
    for (int n = 0; n < 2; ++n){ cmn[nh][n] = BIGF; cmx[nh][n] = 0.f; cfl[nh][n] = 0; }

  #pragma unroll
  for (int mh = 0; mh < 2; ++mh)
    #pragma unroll
    for (int m = 0; m < 4; ++m)
      #pragma unroll
      for (int r = 0; r < 4; ++r){
        int i = i0 + mh * 128 + wr * 64 + m * 16 + lg * 4 + r;
        int li = labels[i];
        float xi = exx[i];
        float hpi = hpos[i];
        float mn = BIGF, mx = 0.f; int fl = 0;
        #pragma unroll
        for (int nh = 0; nh < 2; ++nh)
          #pragma unroll
          for (int n = 0; n < 2; ++n){
            float d2 = xi + xj[nh][n] - 2.f * acc[mh][nh][m][n][r];
            float d  = sqrtf(fmaxf(d2, EPSC));
            bool an = (li != jl[nh][n]);
            bool g  = an && (d > hpi);
            mn = fminf(mn, g ? d : BIGF);
            mx = fmaxf(mx, an ? d : 0.f);
            fl |= (g ? 1 : 0) | (an ? 2 : 0);
            if (docol){
              bool gc = an && (d > hpj[nh][n]);
              cmn[nh][n] = fminf(cmn[nh][n], gc ? d : BIGF);
              cmx[nh][n] = fmaxf(cmx[nh][n], an ? d : 0.f);
              cfl[nh][n] |= (gc ? 1 : 0) | (an ? 2 : 0);
            }
          }
        #pragma unroll
        for (int s = 1; s < 16; s <<= 1){
          mn = fminf(mn, __shfl_xor(mn, s));
          mx = fmaxf(mx, __shfl_xor(mx, s));
          fl |= __shfl_xor(fl, s);
        }
        if (lr == 0){
          atomicMin(&mnv[i], __float_as_uint(mn));
          atomicMax(&mxv[i], __float_as_uint(mx));
          if (fl) atomicOr(&flv[i], (unsigned)fl);
        }
      }
  if (docol){
    #pragma unroll
    for (int nh = 0; nh < 2; ++nh)
      #pragma unroll
      for (int n = 0; n < 2; ++n){
        float mn = cmn[nh][n], mx = cmx[nh][n]; int fl = cfl[nh][n];
        #pragma unroll
        for (int s = 16; s < 64; s <<= 1){
          mn = fminf(mn, __shfl_xor(mn, s));
          mx = fmaxf(mx, __shfl_xor(mx, s));
          fl |= __shfl_xor(fl, s);
        }
        if (lg == 0){
          int j = j0 + nh * 128 + wc * 32 + n * 16 + lr;
          atomicMin(&mn0[j], __float_as_uint(mn));
          atomicMax(&mx0[j], __float_as_uint(mx));
          if (fl) atomicOr(&fl0[j], (unsigned)fl);
        }
      }
  }
}

// ---------------- combine + loss ----------------
__global__ __launch_bounds__(256) void k_final(const float* __restrict__ hpos,
    const unsigned* __restrict__ mn0, const unsigned* __restrict__ mx0,
    const unsigned* __restrict__ fl0, const unsigned* __restrict__ mn1,
    const unsigned* __restrict__ mx1, const unsigned* __restrict__ fl1,
    const float* __restrict__ margin, float* __restrict__ out, int B){
  float part = 0.f;
  float mar = margin[0];
  for (int i = threadIdx.x; i < B; i += blockDim.x){
    float h_out = fminf(__uint_as_float(mn0[i]), __uint_as_float(mn1[i]));
    unsigned f0 = fl0[i], f1 = fl1[i];
    float ni  = (!(f0 & 1u)) ? __uint_as_float(mx0[i]) : ((f0 & 2u) ? BIGF : 0.f);
    float nic = (!(f1 & 1u)) ? __uint_as_float(mx1[i]) : ((f1 & 2u) ? BIGF : 0.f);
    float h_in = fmaxf(ni, nic);
    float hneg = fminf(h_out, h_in);
    float t = hpos[i] - hneg + mar;
    part += fmaxf(t, 0.f);
  }
  float tot = block_reduce_sum(part);
  if (threadIdx.x == 0) out[0] = tot / (float)B;
}

extern "C" void kernel_launch(void* const* d_in, const int* in_sizes, int n_in,
                              void* d_out, int out_size, void* d_ws, size_t ws_size,
                              hipStream_t stream){
  const float* emb    = (const float*)d_in[0];
  const int*   labels = (const int*)d_in[1];
  const float* cval   = (const float*)d_in[2];
  const float* ccnt   = (const float*)d_in[3];
  const float* margin = (const float*)d_in[4];
  float* out = (float*)d_out;

  int B = in_sizes[1];
  int D = in_sizes[0] / B;
  int C = in_sizes[2] / D;
  const int MMAX = 64;

  char* ws = (char*)d_ws;
  size_t off = 0;
  auto alloc = [&](size_t bytes)->char*{
    char* p = ws + off;
    off = (off + bytes + 255) & ~(size_t)255;
    return p;
  };
  unsigned short* enb = (unsigned short*)alloc((size_t)B * D * 2);
  unsigned short* cnb = (unsigned short*)alloc((size_t)C * D * 2);
  float* exx  = (float*)alloc((size_t)B * 4);
  float* cxx  = (float*)alloc((size_t)C * 4);
  float* hpos = (float*)alloc((size_t)B * 4);
  unsigned* mn0 = (unsigned*)alloc((size_t)B * 4);
  unsigned* mx0 = (unsigned*)alloc((size_t)B * 4);
  unsigned* fl0 = (unsigned*)alloc((size_t)B * 4);
  unsigned* mn1 = (unsigned*)alloc((size_t)B * 4);
  unsigned* mx1 = (unsigned*)alloc((size_t)B * 4);
  unsigned* fl1 = (unsigned*)alloc((size_t)B * 4);
  int* cnt     = (int*)alloc((size_t)C * 4);
  int* members = (int*)alloc((size_t)C * MMAX * 4);
  (void)ws_size; (void)n_in; (void)out_size;

  hipFuncSetAttribute((const void*)k_pd_all,
                      hipFuncAttributeMaxDynamicSharedMemorySize, 131072);

  // setup: one wave per class + flat init of row stats
  int nbSetup = (C + 3) / 4;
  int nbInit  = ((B > C ? B : C) + 255) / 256;
  if (nbInit > nbSetup) nbSetup = nbInit;
  k_setup<<<nbSetup, 256, 0, stream>>>(labels, cnt, members,
                                       mn0, mx0, fl0, mn1, mx1, fl1, B, C, MMAX);

  int nbNorm = B / 4, nbCent = C / 4;
  int R = D >> 9;
  if (R == 4){
    k_prep<4><<<nbNorm + nbCent, 256, 0, stream>>>(emb, cval, ccnt, cnt, members,
                                                   enb, cnb, exx, cxx, D, MMAX, nbNorm);
  } else if (R == 2){
    k_prep<2><<<nbNorm + nbCent, 256, 0, stream>>>(emb, cval, ccnt, cnt, members,
                                                   enb, cnb, exx, cxx, D, MMAX, nbNorm);
  } else {
    k_prep<1><<<nbNorm + nbCent, 256, 0, stream>>>(emb, cval, ccnt, cnt, members,
                                                   enb, cnb, exx, cxx, D, MMAX, nbNorm);
  }

  switch (R){
    case 1: k_hpos<1><<<B/4, 256, 0, stream>>>(enb, cnb, exx, cxx, labels, cnt, members, hpos, D, MMAX); break;
    case 2: k_hpos<2><<<B/4, 256, 0, stream>>>(enb, cnb, exx, cxx, labels, cnt, members, hpos, D, MMAX); break;
    default: k_hpos<4><<<B/4, 256, 0, stream>>>(enb, cnb, exx, cxx, labels, cnt, members, hpos, D, MMAX); break;
  }

  int nby = B / 256, nCx = C / 256;
  int nTri = nby * (nby + 1) / 2;
  k_pd_all<<<nTri + nby * nCx, 512, 131072, stream>>>(
      enb, cnb, exx, cxx, labels, hpos,
      mn0, mx0, fl0, mn1, mx1, fl1, D, nTri, nCx);
  k_final<<<1, 256, 0, stream>>>(hpos, mn0, mx0, fl0, mn1, mx1, fl1, margin, out, B);
}

// Round 9
// 152.984 us; speedup vs baseline: 1.3203x; 1.0225x over previous
//
#include <hip/hip_runtime.h>
#include <hip/hip_bf16.h>

// CaMLoss fused forward for MI355X (gfx950).
// B=4096, D=2048, C=1024. Assumes D%512==0 (R in {1,2,4}), B%256==0, C%256==0.
// enb/cnb stored SLOT-SWIZZLED: within each 64-elem chunk of row i, 8-elem slot
// s lives at s ^ (i&7); ds_read at col ^ ((row&7)<<3) is conflict-free (verified 0).
// k_pd_all (R9): retention pipeline + HOISTED ds_reads (m201 ordering):
//   each phase's register loads are issued right after the previous phase's
//   MFMA (before stage/vmcnt/barrier) so they overlap other waves' MFMA.
//   Publish-lead proof: stage order [B0',A0',A1',B1'] + vmcnt(4)/phase =>
//   half staged at p' is published at barrier(p'+2), >=1 barrier before its
//   hoisted read. Tail gates [2,0,-,-]. Reads/tile/wave = 24 (minimum).

typedef __attribute__((ext_vector_type(8))) short short8;
typedef __attribute__((ext_vector_type(4))) float f32x4;

#define BIGF 1e6f
#define EPSC 1e-12f

__device__ __forceinline__ float bf2f(unsigned short u){
  unsigned int x = ((unsigned int)u) << 16;
  return __uint_as_float(x);
}
__device__ __forceinline__ unsigned short f2bf(float f){
  __hip_bfloat16 h = __float2bfloat16(f);
  return *reinterpret_cast<unsigned short*>(&h);
}

__device__ __forceinline__ float block_reduce_sum(float v){
  __shared__ float red[4];
  int tid = threadIdx.x;
  __syncthreads();
  #pragma unroll
  for (int s = 32; s; s >>= 1) v += __shfl_xor(v, s);
  if ((tid & 63) == 0) red[tid >> 6] = v;
  __syncthreads();
  return red[0] + red[1] + red[2] + red[3];
}

// async global->LDS, 16B per lane, wave-uniform LDS base + lane*16
#define GLL16(gptr, lptr) \
  __builtin_amdgcn_global_load_lds( \
      (const __attribute__((address_space(1))) unsigned int*)(gptr), \
      (__attribute__((address_space(3))) unsigned int*)(lptr), 16, 0, 0)

#define VMWAIT(S) asm volatile("s_waitcnt " S ::: "memory")
#define SBAR()    asm volatile("s_barrier" ::: "memory")

// ---------------- setup: init stats + ballot-based per-class member lists ----------------
__global__ __launch_bounds__(256) void k_setup(const int* __restrict__ labels,
    int* cnt, int* members,
    unsigned* mn0, unsigned* mx0, unsigned* fl0,
    unsigned* mn1, unsigned* mx1, unsigned* fl1,
    int B, int C, int MMAX){
  int gid = blockIdx.x * blockDim.x + threadIdx.x;
  unsigned bigbits = __float_as_uint(BIGF);
  if (gid < B){
    mn0[gid] = bigbits; mx0[gid] = 0u; fl0[gid] = 0u;
    mn1[gid] = bigbits; mx1[gid] = 0u; fl1[gid] = 0u;
  }
  int w = threadIdx.x >> 6, lane = threadIdx.x & 63;
  int c = blockIdx.x * 4 + w;
  if (c >= C) return;                       // wave-uniform
  int base = 0;
  int nit = (B + 63) >> 6;
  for (int itc = 0; itc < nit; ++itc){
    int idx = itc * 64 + lane;
    int lab = (idx < B) ? labels[idx] : -1;
    unsigned long long m = __ballot(lab == c);
    if (lab == c){
      int rk = base + (int)__popcll(m & ((1ull << lane) - 1ull));
      if (rk < MMAX) members[c * MMAX + rk] = idx;
    }
    base += (int)__popcll(m);
  }
  if (lane == 0) cnt[c] = base;
}

// ---------------- prep: normalize embeddings + centers (merged) ----------------
template<int R>   // R = D/512
__global__ __launch_bounds__(256) void k_prep(const float* __restrict__ emb,
    const float* __restrict__ cval, const float* __restrict__ ccnt,
    const int* __restrict__ cnt, const int* __restrict__ members,
    unsigned short* __restrict__ enb, unsigned short* __restrict__ cnb,
    float* __restrict__ exx, float* __restrict__ cxx,
    int D, int MMAX, int nbNorm){
  int w = threadIdx.x >> 6, lane = threadIdx.x & 63;
  if ((int)blockIdx.x < nbNorm){
    int i = blockIdx.x * 4 + w;
    const float* row = emb + (size_t)i * D;
    float v[R][8];
    float ss = 0.f;
    #pragma unroll
    for (int r = 0; r < R; ++r){
      int base = r * 512 + lane * 8;
      float4 a = *reinterpret_cast<const float4*>(&row[base]);
      float4 b = *reinterpret_cast<const float4*>(&row[base + 4]);
      v[r][0]=a.x; v[r][1]=a.y; v[r][2]=a.z; v[r][3]=a.w;
      v[r][4]=b.x; v[r][5]=b.y; v[r][6]=b.z; v[r][7]=b.w;
      #pragma unroll
      for (int k = 0; k < 8; ++k) ss += v[r][k] * v[r][k];
    }
    #pragma unroll
    for (int s = 1; s < 64; s <<= 1) ss += __shfl_xor(ss, s);
    float inv = 1.f / (sqrtf(ss) + EPSC);
    unsigned short* orow = enb + (size_t)i * D;
    int xr = (i & 7) << 3;
    #pragma unroll
    for (int r = 0; r < R; ++r){
      int base = (r * 512 + lane * 8) ^ xr;
      short8 o;
      #pragma unroll
      for (int k = 0; k < 8; ++k) o[k] = (short)f2bf(v[r][k] * inv);
      *reinterpret_cast<short8*>(&orow[base]) = o;
    }
    if (lane == 0) exx[i] = ss * inv * inv;
  } else {
    int c = ((int)blockIdx.x - nbNorm) * 4 + w;
    int n = cnt[c], m = n < MMAX ? n : MMAX;
    float acc[R][8];
    #pragma unroll
    for (int r = 0; r < R; ++r)
      #pragma unroll
      for (int k = 0; k < 8; ++k) acc[r][k] = 0.f;
    for (int e = 0; e < m; ++e){
      const float* row = emb + (size_t)members[c * MMAX + e] * D;
      #pragma unroll
      for (int r = 0; r < R; ++r){
        int base = r * 512 + lane * 8;
        float4 a = *reinterpret_cast<const float4*>(&row[base]);
        float4 b = *reinterpret_cast<const float4*>(&row[base + 4]);
        acc[r][0]+=a.x; acc[r][1]+=a.y; acc[r][2]+=a.z; acc[r][3]+=a.w;
        acc[r][4]+=b.x; acc[r][5]+=b.y; acc[r][6]+=b.z; acc[r][7]+=b.w;
      }
    }
    float cf = (float)n;
    float ss = 0.f;
    #pragma unroll
    for (int r = 0; r < R; ++r){
      int base = r * 512 + lane * 8;
      float4 u0 = *reinterpret_cast<const float4*>(&ccnt[(size_t)c * D + base]);
      float4 u1 = *reinterpret_cast<const float4*>(&ccnt[(size_t)c * D + base + 4]);
      float4 w0 = *reinterpret_cast<const float4*>(&cval[(size_t)c * D + base]);
      float4 w1 = *reinterpret_cast<const float4*>(&cval[(size_t)c * D + base + 4]);
      float uc[8] = {u0.x,u0.y,u0.z,u0.w,u1.x,u1.y,u1.z,u1.w};
      float wv[8] = {w0.x,w0.y,w0.z,w0.w,w1.x,w1.y,w1.z,w1.w};
      #pragma unroll
      for (int k = 0; k < 8; ++k){
        float u = uc[k] + cf;
        float vv = wv[k] + acc[r][k];
        float ce = (u > 0.f) ? (vv / fmaxf(u, 1.f)) : 0.f;
        acc[r][k] = ce; ss += ce * ce;
      }
    }
    #pragma unroll
    for (int s = 1; s < 64; s <<= 1) ss += __shfl_xor(ss, s);
    float inv = 1.f / (sqrtf(ss) + EPSC);
    int xr = (c & 7) << 3;
    #pragma unroll
    for (int r = 0; r < R; ++r){
      int base = (r * 512 + lane * 8) ^ xr;
      short8 o;
      #pragma unroll
      for (int k = 0; k < 8; ++k) o[k] = (short)f2bf(acc[r][k] * inv);
      *reinterpret_cast<short8*>(&cnb[(size_t)c * D + base]) = o;
    }
    if (lane == 0) cxx[c] = ss * inv * inv;
  }
}

// ---------------- hardest positive: one wave per row ----------------
template<int NCH>
__global__ __launch_bounds__(256) void k_hpos(const unsigned short* __restrict__ enb,
    const unsigned short* __restrict__ cnb, const float* __restrict__ exx,
    const float* __restrict__ cxx, const int* __restrict__ labels,
    const int* __restrict__ cnt, const int* __restrict__ members,
    float* __restrict__ hpos, int D, int MMAX){
  int w = threadIdx.x >> 6, lane = threadIdx.x & 63;
  int i = blockIdx.x * 4 + w;
  int li = labels[i];
  const unsigned short* arow = enb + (size_t)i * D;
  int xri = (i & 7) << 3;
  float av[NCH][8];
  #pragma unroll
  for (int ch = 0; ch < NCH; ++ch){
    short8 a8 = *reinterpret_cast<const short8*>(&arow[(ch * 512 + lane * 8) ^ xri]);
    #pragma unroll
    for (int k = 0; k < 8; ++k) av[ch][k] = bf2f((unsigned short)a8[k]);
  }
  float xi = exx[i];
  float hp = 0.f;
  int m = cnt[li] < MMAX ? cnt[li] : MMAX;
  for (int e = 0; e < m; ++e){
    int j = members[li * MMAX + e];
    if (j == i) continue;                     // wave-uniform
    const unsigned short* brow = enb + (size_t)j * D;
    int xrj = (j & 7) << 3;
    float p = 0.f;
    #pragma unroll
    for (int ch = 0; ch < NCH; ++ch){
      short8 b8 = *reinterpret_cast<const short8*>(&brow[(ch * 512 + lane * 8) ^ xrj]);
      #pragma unroll
      for (int k = 0; k < 8; ++k) p += av[ch][k] * bf2f((unsigned short)b8[k]);
    }
    #pragma unroll
    for (int s = 1; s < 64; s <<= 1) p += __shfl_xor(p, s);
    float d2 = xi + exx[j] - 2.f * p;
    hp = fmaxf(hp, sqrtf(fmaxf(d2, EPSC)));
  }
  {
    const unsigned short* brow = cnb + (size_t)li * D;
    int xrc = (li & 7) << 3;
    float p = 0.f;
    #pragma unroll
    for (int ch = 0; ch < NCH; ++ch){
      short8 b8 = *reinterpret_cast<const short8*>(&brow[(ch * 512 + lane * 8) ^ xrc]);
      #pragma unroll
      for (int k = 0; k < 8; ++k) p += av[ch][k] * bf2f((unsigned short)b8[k]);
    }
    #pragma unroll
    for (int s = 1; s < 64; s <<= 1) p += __shfl_xor(p, s);
    float d2 = xi + cxx[li] - 2.f * p;
    hp = fmaxf(hp, sqrtf(fmaxf(d2, EPSC)));
  }
  if (lane == 0) hpos[i] = hp;
}

// ---------------- merged distance pass: hoisted-read retention pipeline 256^2 ----------------
#define PD_STAGE(SB, KIND, KT) do { \
    unsigned short* dst_ = (SB) + (KIND) * 8192 + wid * (16 * 64); \
    const unsigned short* src_ = ((KIND) < 2 \
        ? gA + (size_t)((KIND) * 128) * D \
        : gB + (size_t)(((KIND) - 2) * 128) * D) + (KT); \
    GLL16(src_, dst_); \
    GLL16(src_ + (size_t)8 * D, dst_ + 8 * 64); \
  } while (0)

#define RD_A(DST, HP) do { \
    _Pragma("unroll") \
    for (int m_ = 0; m_ < 4; ++m_){ \
      DST[m_][0] = *reinterpret_cast<const short8*>(&(HP)[aoff[m_][0]]); \
      DST[m_][1] = *reinterpret_cast<const short8*>(&(HP)[aoff[m_][1]]); \
    } } while (0)

#define RD_B(HP) do { \
    _Pragma("unroll") \
    for (int n_ = 0; n_ < 2; ++n_){ \
      b[n_][0] = *reinterpret_cast<const short8*>(&(HP)[boff[n_][0]]); \
      b[n_][1] = *reinterpret_cast<const short8*>(&(HP)[boff[n_][1]]); \
    } } while (0)

#define LGKM0() do { VMWAIT("lgkmcnt(0)"); __builtin_amdgcn_sched_barrier(0); } while (0)

#define MFMA16(AV, MH, NH) do { \
    __builtin_amdgcn_s_setprio(1); \
    _Pragma("unroll") \
    for (int m_ = 0; m_ < 4; ++m_) \
      _Pragma("unroll") \
      for (int n_ = 0; n_ < 2; ++n_) \
        _Pragma("unroll") \
        for (int ks_ = 0; ks_ < 2; ++ks_) \
          acc[MH][NH][m_][n_] = __builtin_amdgcn_mfma_f32_16x16x32_bf16( \
              AV[m_][ks_], b[n_][ks_], acc[MH][NH][m_][n_], 0, 0, 0); \
    __builtin_amdgcn_s_setprio(0); } while (0)

__global__ __launch_bounds__(512, 2) void k_pd_all(
    const unsigned short* __restrict__ enb,
    const unsigned short* __restrict__ cnb,
    const float* __restrict__ exx, const float* __restrict__ cxx,
    const int* __restrict__ labels, const float* __restrict__ hpos,
    unsigned* __restrict__ mn0, unsigned* __restrict__ mx0, unsigned* __restrict__ fl0,
    unsigned* __restrict__ mn1, unsigned* __restrict__ mx1, unsigned* __restrict__ fl1,
    int D, int nTri, int nCx)
{
  extern __shared__ unsigned short sm[];           // 2 dbuf x 4 half-slots x 16KB = 128KB
  // bijective XCD swizzle (m204)
  const int nwg = gridDim.x;
  const int orig = blockIdx.x;
  const int q8 = nwg >> 3, r8 = nwg & 7;
  const int xcd = orig & 7, idx = orig >> 3;
  const int t = (xcd < r8 ? xcd * (q8 + 1) : r8 * (q8 + 1) + (xcd - r8) * q8) + idx;

  const bool pdc = (t >= nTri);
  int bx, by;
  if (!pdc){
    int b_ = (int)((sqrtf(8.f * (float)t + 1.f) - 1.f) * 0.5f);
    while ((b_ + 1) * (b_ + 2) / 2 <= t) ++b_;
    while (b_ * (b_ + 1) / 2 > t) --b_;
    by = b_; bx = t - b_ * (b_ + 1) / 2;           // bx <= by
  } else {
    int u = t - nTri;
    by = u / nCx; bx = u - by * nCx;
  }
  const unsigned short* cmat = pdc ? cnb : enb;
  const float* cxv = pdc ? cxx : exx;
  unsigned* mnv = pdc ? mn1 : mn0;
  unsigned* mxv = pdc ? mx1 : mx0;
  unsigned* flv = pdc ? fl1 : fl0;

  const int j0 = bx * 256, i0 = by * 256;
  const int tid = threadIdx.x;
  const int wid = tid >> 6, lane = tid & 63;
  const int wr = wid >> 2, wc = wid & 3;           // 2M x 4N wave bands
  const int lr = lane & 15, lg = lane >> 4;

  // stage source: wave wid stages rows [wid*16, wid*16+16) of each half
  const int srow = wid * 16 + (lane >> 3);
  const int scol = (lane & 7) * 8;
  const unsigned short* gA = enb  + (size_t)(i0 + srow) * D + scol;
  const unsigned short* gB = cmat + (size_t)(j0 + srow) * D + scol;

  // ds_read offsets within a 16KB half [128][64] (swizzled)
  int aoff[4][2], boff[2][2];
  #pragma unroll
  for (int m = 0; m < 4; ++m){
    int ra = wr * 64 + m * 16 + lr;
    #pragma unroll
    for (int ks = 0; ks < 2; ++ks)
      aoff[m][ks] = ra * 64 + ((ks * 32 + lg * 8) ^ ((ra & 7) << 3));
  }
  #pragma unroll
  for (int n = 0; n < 2; ++n){
    int rb = wc * 32 + n * 16 + lr;
    #pragma unroll
    for (int ks = 0; ks < 2; ++ks)
      boff[n][ks] = rb * 64 + ((ks * 32 + lg * 8) ^ ((rb & 7) << 3));
  }

  f32x4 acc[2][2][4][2];
  #pragma unroll
  for (int mh = 0; mh < 2; ++mh)
    #pragma unroll
    for (int nh = 0; nh < 2; ++nh)
      #pragma unroll
      for (int m = 0; m < 4; ++m)
        #pragma unroll
        for (int n = 0; n < 2; ++n)
          acc[mh][nh][m][n] = (f32x4){0.f, 0.f, 0.f, 0.f};

  short8 a0[4][2], a1[4][2], b[2][2];

  const int nt = D >> 6;
  // prologue: stage all 4 halves of tile 0, drain fully once
  PD_STAGE(sm, 0, 0); PD_STAGE(sm, 1, 0); PD_STAGE(sm, 2, 0); PD_STAGE(sm, 3, 0);
  VMWAIT("vmcnt(0)");
  SBAR();

  for (int it = 0; it < nt; ++it){
    const unsigned short* db = sm + (size_t)(it & 1) * 32768;
    unsigned short* sb = sm + (size_t)((it & 1) ^ 1) * 32768;
    const bool hn = (it + 1 < nt);
    const int ktn = (it + 1) << 6;
    // phase 0: hoisted reads A0,B0 (published >=1 barrier ago); stage B0'
    RD_A(a0, db);
    RD_B(db + 2 * 8192);
    if (hn){ PD_STAGE(sb, 2, ktn); VMWAIT("vmcnt(4)"); } else { VMWAIT("vmcnt(2)"); }
    SBAR();
    LGKM0();
    MFMA16(a0, 0, 0);
    // phase 1: hoisted read A1; stage A0'
    RD_A(a1, db + 8192);
    if (hn){ PD_STAGE(sb, 0, ktn); VMWAIT("vmcnt(4)"); } else { VMWAIT("vmcnt(0)"); }
    SBAR();
    LGKM0();
    MFMA16(a1, 1, 0);
    // phase 2: hoisted read B1; stage A1'
    RD_B(db + 3 * 8192);
    if (hn){ PD_STAGE(sb, 1, ktn); VMWAIT("vmcnt(4)"); }
    SBAR();
    LGKM0();
    MFMA16(a1, 1, 1);
    // phase 3: pure-register MFMA; stage B1'
    if (hn){ PD_STAGE(sb, 3, ktn); VMWAIT("vmcnt(4)"); }
    SBAR();
    MFMA16(a0, 0, 1);
  }

  // epilogue: rows i = i0 + mh*128 + wr*64 + m*16 + lg*4 + r
  //           cols j = j0 + nh*128 + wc*32 + n*16 + lr
  const bool docol = (!pdc) && (bx != by);
  int jl[2][2]; float xj[2][2], hpj[2][2];
  #pragma unroll
  for (int nh = 0; nh < 2; ++nh)
    #pragma unroll
    for (int n = 0; n < 2; ++n){
      int j = j0 + nh * 128 + wc * 32 + n * 16 + lr;
      jl[nh][n] = pdc ? j : labels[j];
      xj[nh][n] = cxv[j];
      hpj[nh][n] = docol ? hpos[j] : 0.f;
    }
  float cmn[2][2], cmx[2][2]; int cfl[2][2];
  #pragma unroll
  for (int nh = 0; nh < 2; ++nh)
    #pragma unroll
    for (int n = 0; n < 2; ++n){ cmn[nh][n] = BIGF; cmx[nh][n] = 0.f; cfl[nh][n] = 0; }

  #pragma unroll
  for (int mh = 0; mh < 2; ++mh)
    #pragma unroll
    for (int m = 0; m < 4; ++m)
      #pragma unroll
      for (int r = 0; r < 4; ++r){
        int i = i0 + mh * 128 + wr * 64 + m * 16 + lg * 4 + r;
        int li = labels[i];
        float xi = exx[i];
        float hpi = hpos[i];
        float mn = BIGF, mx = 0.f; int fl = 0;
        #pragma unroll
        for (int nh = 0; nh < 2; ++nh)
          #pragma unroll
          for (int n = 0; n < 2; ++n){
            float d2 = xi + xj[nh][n] - 2.f * acc[mh][nh][m][n][r];
            float d  = sqrtf(fmaxf(d2, EPSC));
            bool an = (li != jl[nh][n]);
            bool g  = an && (d > hpi);
            mn = fminf(mn, g ? d : BIGF);
            mx = fmaxf(mx, an ? d : 0.f);
            fl |= (g ? 1 : 0) | (an ? 2 : 0);
            if (docol){
              bool gc = an && (d > hpj[nh][n]);
              cmn[nh][n] = fminf(cmn[nh][n], gc ? d : BIGF);
              cmx[nh][n] = fmaxf(cmx[nh][n], an ? d : 0.f);
              cfl[nh][n] |= (gc ? 1 : 0) | (an ? 2 : 0);
            }
          }
        #pragma unroll
        for (int s = 1; s < 16; s <<= 1){
          mn = fminf(mn, __shfl_xor(mn, s));
          mx = fmaxf(mx, __shfl_xor(mx, s));
          fl |= __shfl_xor(fl, s);
        }
        if (lr == 0){
          atomicMin(&mnv[i], __float_as_uint(mn));
          atomicMax(&mxv[i], __float_as_uint(mx));
          if (fl) atomicOr(&flv[i], (unsigned)fl);
        }
      }
  if (docol){
    #pragma unroll
    for (int nh = 0; nh < 2; ++nh)
      #pragma unroll
      for (int n = 0; n < 2; ++n){
        float mn = cmn[nh][n], mx = cmx[nh][n]; int fl = cfl[nh][n];
        #pragma unroll
        for (int s = 16; s < 64; s <<= 1){
          mn = fminf(mn, __shfl_xor(mn, s));
          mx = fmaxf(mx, __shfl_xor(mx, s));
          fl |= __shfl_xor(fl, s);
        }
        if (lg == 0){
          int j = j0 + nh * 128 + wc * 32 + n * 16 + lr;
          atomicMin(&mn0[j], __float_as_uint(mn));
          atomicMax(&mx0[j], __float_as_uint(mx));
          if (fl) atomicOr(&fl0[j], (unsigned)fl);
        }
      }
  }
}

// ---------------- combine + loss ----------------
__global__ __launch_bounds__(256) void k_final(const float* __restrict__ hpos,
    const unsigned* __restrict__ mn0, const unsigned* __restrict__ mx0,
    const unsigned* __restrict__ fl0, const unsigned* __restrict__ mn1,
    const unsigned* __restrict__ mx1, const unsigned* __restrict__ fl1,
    const float* __restrict__ margin, float* __restrict__ out, int B){
  float part = 0.f;
  float mar = margin[0];
  for (int i = threadIdx.x; i < B; i += blockDim.x){
    float h_out = fminf(__uint_as_float(mn0[i]), __uint_as_float(mn1[i]));
    unsigned f0 = fl0[i], f1 = fl1[i];
    float ni  = (!(f0 & 1u)) ? __uint_as_float(mx0[i]) : ((f0 & 2u) ? BIGF : 0.f);
    float nic = (!(f1 & 1u)) ? __uint_as_float(mx1[i]) : ((f1 & 2u) ? BIGF : 0.f);
    float h_in = fmaxf(ni, nic);
    float hneg = fminf(h_out, h_in);
    float t = hpos[i] - hneg + mar;
    part += fmaxf(t, 0.f);
  }
  float tot = block_reduce_sum(part);
  if (threadIdx.x == 0) out[0] = tot / (float)B;
}

extern "C" void kernel_launch(void* const* d_in, const int* in_sizes, int n_in,
                              void* d_out, int out_size, void* d_ws, size_t ws_size,
                              hipStream_t stream){
  const float* emb    = (const float*)d_in[0];
  const int*   labels = (const int*)d_in[1];
  const float* cval   = (const float*)d_in[2];
  const float* ccnt   = (const float*)d_in[3];
  const float* margin = (const float*)d_in[4];
  float* out = (float*)d_out;

  int B = in_sizes[1];
  int D = in_sizes[0] / B;
  int C = in_sizes[2] / D;
  const int MMAX = 64;

  char* ws = (char*)d_ws;
  size_t off = 0;
  auto alloc = [&](size_t bytes)->char*{
    char* p = ws + off;
    off = (off + bytes + 255) & ~(size_t)255;
    return p;
  };
  unsigned short* enb = (unsigned short*)alloc((size_t)B * D * 2);
  unsigned short* cnb = (unsigned short*)alloc((size_t)C * D * 2);
  float* exx  = (float*)alloc((size_t)B * 4);
  float* cxx  = (float*)alloc((size_t)C * 4);
  float* hpos = (float*)alloc((size_t)B * 4);
  unsigned* mn0 = (unsigned*)alloc((size_t)B * 4);
  unsigned* mx0 = (unsigned*)alloc((size_t)B * 4);
  unsigned* fl0 = (unsigned*)alloc((size_t)B * 4);
  unsigned* mn1 = (unsigned*)alloc((size_t)B * 4);
  unsigned* mx1 = (unsigned*)alloc((size_t)B * 4);
  unsigned* fl1 = (unsigned*)alloc((size_t)B * 4);
  int* cnt     = (int*)alloc((size_t)C * 4);
  int* members = (int*)alloc((size_t)C * MMAX * 4);
  (void)ws_size; (void)n_in; (void)out_size;

  hipFuncSetAttribute((const void*)k_pd_all,
                      hipFuncAttributeMaxDynamicSharedMemorySize, 131072);

  // setup: one wave per class + flat init of row stats
  int nbSetup = (C + 3) / 4;
  int nbInit  = ((B > C ? B : C) + 255) / 256;
  if (nbInit > nbSetup) nbSetup = nbInit;
  k_setup<<<nbSetup, 256, 0, stream>>>(labels, cnt, members,
                                       mn0, mx0, fl0, mn1, mx1, fl1, B, C, MMAX);

  int nbNorm = B / 4, nbCent = C / 4;
  int R = D >> 9;
  if (R == 4){
    k_prep<4><<<nbNorm + nbCent, 256, 0, stream>>>(emb, cval, ccnt, cnt, members,
                                                   enb, cnb, exx, cxx, D, MMAX, nbNorm);
  } else if (R == 2){
    k_prep<2><<<nbNorm + nbCent, 256, 0, stream>>>(emb, cval, ccnt, cnt, members,
                                                   enb, cnb, exx, cxx, D, MMAX, nbNorm);
  } else {
    k_prep<1><<<nbNorm + nbCent, 256, 0, stream>>>(emb, cval, ccnt, cnt, members,
                                                   enb, cnb, exx, cxx, D, MMAX, nbNorm);
  }

  switch (R){
    case 1: k_hpos<1><<<B/4, 256, 0, stream>>>(enb, cnb, exx, cxx, labels, cnt, members, hpos, D, MMAX); break;
    case 2: k_hpos<2><<<B/4, 256, 0, stream>>>(enb, cnb, exx, cxx, labels, cnt, members, hpos, D, MMAX); break;
    default: k_hpos<4><<<B/4, 256, 0, stream>>>(enb, cnb, exx, cxx, labels, cnt, members, hpos, D, MMAX); break;
  }

  int nby = B / 256, nCx = C / 256;
  int nTri = nby * (nby + 1) / 2;
  k_pd_all<<<nTri + nby * nCx, 512, 131072, stream>>>(
      enb, cnb, exx, cxx, labels, hpos,
      mn0, mx0, fl0, mn1, mx1, fl1, D, nTri, nCx);
  k_final<<<1, 256, 0, stream>>>(hpos, mn0, mx0, fl0, mn1, mx1, fl1, margin, out, B);
}